// Round 10
// baseline (415.827 us; speedup 1.0000x reference)
//
#include <hip/hip_runtime.h>

typedef unsigned short u16;
typedef unsigned int   u32;
typedef __bf16 bf16x8 __attribute__((ext_vector_type(8)));
typedef float  f32x4  __attribute__((ext_vector_type(4)));
typedef u16    u16x4  __attribute__((ext_vector_type(4)));
typedef u16    u16x8  __attribute__((ext_vector_type(8)));

// ---------- helpers ----------
__device__ __forceinline__ u16 f2bf(float f) {
  u32 u = __float_as_uint(f);
  u32 r = u + 0x7fffu + ((u >> 16) & 1u);   // RTNE
  return (u16)(r >> 16);
}

__device__ __forceinline__ void gl16(const void* g, void* l) {
  __builtin_amdgcn_global_load_lds((__attribute__((address_space(1))) void*)(g),
                                   (__attribute__((address_space(3))) void*)(l),
                                   16, 0, 0);
}

#define WAITVM4  asm volatile("s_waitcnt vmcnt(4)" ::: "memory")
#define WAITVM0  asm volatile("s_waitcnt vmcnt(0)" ::: "memory")
#define WAITLG0  asm volatile("s_waitcnt lgkmcnt(0)" ::: "memory")
#define BAR()    asm volatile("s_barrier" ::: "memory")
#define SCHEDB() __builtin_amdgcn_sched_barrier(0)

// ---------- prep_a: cvt(hidden) + wqa/wkva transpose into wab_t + pad zero ----------
__device__ __forceinline__ void tr_tile(const float* __restrict__ W, u16* __restrict__ Wt,
                                        int K, int N, int NT, int idx, float (*tile)[65]) {
  const int tid = threadIdx.x;
  const int nt = idx % NT, kt = idx / NT;
  const int n0 = nt * 64, k0 = kt * 32;
  {
    const int r = tid >> 3, c8 = (tid & 7) << 3;
    const float* src = W + (size_t)(k0 + r) * N + n0 + c8;
    float4 a = *(const float4*)src;
    float4 b = *(const float4*)(src + 4);
    tile[r][c8 + 0] = a.x; tile[r][c8 + 1] = a.y; tile[r][c8 + 2] = a.z; tile[r][c8 + 3] = a.w;
    tile[r][c8 + 4] = b.x; tile[r][c8 + 5] = b.y; tile[r][c8 + 6] = b.z; tile[r][c8 + 7] = b.w;
  }
  __syncthreads();
  const int n = tid >> 2, kg = (tid & 3) << 3;
  u16x8 o;
  #pragma unroll
  for (int j = 0; j < 8; ++j) o[j] = f2bf(tile[kg + j][n]);
  *(u16x8*)(Wt + (size_t)(n0 + n) * K + k0 + kg) = o;
}

// wab_t: merged [2304][5120]: rows 0..1535 = wqa^T, 1536..2111 = wkva^T, 2112..2303 = 0
__global__ __launch_bounds__(256) void prep_a(const float* __restrict__ hidden, u16* __restrict__ hs_bf,
                                              const float* __restrict__ wqa,
                                              const float* __restrict__ wkva, u16* __restrict__ wab_t) {
  __shared__ float tile[32][65];
  const int b = blockIdx.x, tid = threadIdx.x;
  if (b < 640) {                       // cvt: hidden [2048][5120] f32 -> bf16
    const float4* xin = (const float4*)hidden;
    #pragma unroll
    for (int j = 0; j < 8; ++j) {
      int u = b * 2048 + j * 256 + tid;
      float4 a = xin[u * 2], c = xin[u * 2 + 1];
      u16x8 o;
      o[0] = f2bf(a.x); o[1] = f2bf(a.y); o[2] = f2bf(a.z); o[3] = f2bf(a.w);
      o[4] = f2bf(c.x); o[5] = f2bf(c.y); o[6] = f2bf(c.z); o[7] = f2bf(c.w);
      *(u16x8*)(hs_bf + (size_t)u * 8) = o;
    }
  } else if (b < 4480) {               // w_q_a [5120][1536] -> wab_t rows 0..1535
    tr_tile(wqa, wab_t, 5120, 1536, 24, b - 640, tile);
  } else if (b < 5920) {               // w_kv_a [5120][576] -> wab_t rows 1536..2111
    tr_tile(wkva, wab_t + (size_t)1536 * 5120, 5120, 576, 9, b - 4480, tile);
  } else {                             // zero wab_t rows 2112..2303 (480 blocks)
    size_t off = (size_t)(b - 5920) * 4096 + tid * 16;
    u16x8 z = {};
    *(u16x8*)((char*)wab_t + (size_t)2112 * 5120 * 2 + off) = z;
  }
}

// ---------- shared 8-phase 256x256 GEMM body ----------
// EPI=0: f32 C   EPI=1: q->rope->q_all   EPI=2: kv->k_all/v_big
template<int EPI>
__device__ __forceinline__ void gemm8_body(char* lds,
                                           const u16* __restrict__ A,
                                           const u16* __restrict__ Bt,
                                           int N, int K, int wg, int nwg, int nbx,
                                           int nkt, int kt0,
                                           const int* __restrict__ pos,
                                           u16* __restrict__ q_all,
                                           u16* __restrict__ k_all,
                                           u16* __restrict__ v_big,
                                           float* __restrict__ Cf) {
  const int tid = threadIdx.x;
  const int lane = tid & 63, wid = tid >> 6;
  const int wr = wid >> 2, wc = wid & 3;
  const int lr = lane & 15, lg = lane >> 4;

  const int swz = ((nwg & 7) == 0) ? ((wg & 7) * (nwg >> 3) + (wg >> 3)) : wg;
  const int bx = swz % nbx, by = swz / nbx;
  const int m0 = by << 8, n0 = bx << 8;

  const size_t rs = (size_t)K << 1;
  const char* Ab = (const char*)A;
  const char* Bb = (const char*)Bt;

  const int sofs = tid << 4;
  const int srow = sofs >> 7;
  const int scol = ((((sofs >> 4) & 7) ^ (srow & 7)) << 4);

  const int axor = lr & 7;
  const int sx0 = (lg ^ axor) << 4;
  const int sx1 = ((4 | lg) ^ axor) << 4;
  const int bcolbase = (wc & 1) << 13;

  f32x4 acc[8][4] = {};

#define ASL(p,h) ((((p) << 1) | (h)) << 14)
#define BSL(p,h) (65536 + ((((p) << 1) | (h)) << 14))
#define STAGE_HALF(gb, grow0, kt, slot)                                              \
  { const char* _s = (gb) + (size_t)(grow0) * rs + ((size_t)((kt) + kt0) << 7) + scol; \
    gl16(_s, lds + (slot) + sofs);                                                   \
    gl16(_s + (rs << 6), lds + (slot) + sofs + 8192); }

  STAGE_HALF(Ab, m0 + srow,       0, ASL(0,0));
  STAGE_HALF(Ab, m0 + 128 + srow, 0, ASL(0,1));
  STAGE_HALF(Bb, n0 + srow,       0, BSL(0,0));
  STAGE_HALF(Bb, n0 + 128 + srow, 0, BSL(0,1));
  if (nkt > 1) {
    STAGE_HALF(Bb, n0 + srow,       1, BSL(1,0));
    STAGE_HALF(Bb, n0 + 128 + srow, 1, BSL(1,1));
    WAITVM4;
  } else {
    WAITVM0;
  }
  BAR();

  for (int b = 0; b < nkt; ++b) {
    const int p = b & 1;
    const int abase = ASL(p, wr);
    const int bbase = BSL(p, (wc >> 1)) + bcolbase;
    bf16x8 aR[4][2], bR[4][2];

    #pragma unroll
    for (int m = 0; m < 4; ++m) {
      aR[m][0] = *(const bf16x8*)(lds + abase + (m * 16 + lr) * 128 + sx0);
      aR[m][1] = *(const bf16x8*)(lds + abase + (m * 16 + lr) * 128 + sx1);
    }
    #pragma unroll
    for (int n = 0; n < 2; ++n) {
      bR[n][0] = *(const bf16x8*)(lds + bbase + (n * 16 + lr) * 128 + sx0);
      bR[n][1] = *(const bf16x8*)(lds + bbase + (n * 16 + lr) * 128 + sx1);
    }
    if (b + 1 < nkt) { STAGE_HALF(Ab, m0 + srow, b + 1, ASL((b + 1) & 1, 0)); }
    BAR(); WAITLG0; SCHEDB();
    __builtin_amdgcn_s_setprio(1);
    #pragma unroll
    for (int kf = 0; kf < 2; ++kf)
      #pragma unroll
      for (int m = 0; m < 4; ++m)
        #pragma unroll
        for (int n = 0; n < 2; ++n)
          acc[m][n] = __builtin_amdgcn_mfma_f32_16x16x32_bf16(aR[m][kf], bR[n][kf], acc[m][n], 0, 0, 0);
    __builtin_amdgcn_s_setprio(0); SCHEDB();
    BAR();

    #pragma unroll
    for (int n = 2; n < 4; ++n) {
      bR[n][0] = *(const bf16x8*)(lds + bbase + (n * 16 + lr) * 128 + sx0);
      bR[n][1] = *(const bf16x8*)(lds + bbase + (n * 16 + lr) * 128 + sx1);
    }
    if (b + 1 < nkt) { STAGE_HALF(Ab, m0 + 128 + srow, b + 1, ASL((b + 1) & 1, 1)); }
    BAR(); WAITLG0; SCHEDB();
    __builtin_amdgcn_s_setprio(1);
    #pragma unroll
    for (int kf = 0; kf < 2; ++kf)
      #pragma unroll
      for (int m = 0; m < 4; ++m)
        #pragma unroll
        for (int n = 2; n < 4; ++n)
          acc[m][n] = __builtin_amdgcn_mfma_f32_16x16x32_bf16(aR[m][kf], bR[n][kf], acc[m][n], 0, 0, 0);
    __builtin_amdgcn_s_setprio(0); SCHEDB();
    BAR();

    #pragma unroll
    for (int m = 0; m < 4; ++m) {
      aR[m][0] = *(const bf16x8*)(lds + abase + ((m + 4) * 16 + lr) * 128 + sx0);
      aR[m][1] = *(const bf16x8*)(lds + abase + ((m + 4) * 16 + lr) * 128 + sx1);
    }
    if (b + 2 < nkt) { STAGE_HALF(Bb, n0 + srow, b + 2, BSL(p, 0)); }
    BAR(); WAITLG0; SCHEDB();
    __builtin_amdgcn_s_setprio(1);
    #pragma unroll
    for (int kf = 0; kf < 2; ++kf)
      #pragma unroll
      for (int m = 0; m < 4; ++m)
        #pragma unroll
        for (int n = 0; n < 2; ++n)
          acc[m + 4][n] = __builtin_amdgcn_mfma_f32_16x16x32_bf16(aR[m][kf], bR[n][kf], acc[m + 4][n], 0, 0, 0);
    __builtin_amdgcn_s_setprio(0); SCHEDB();
    BAR();

    if (b + 2 < nkt) { STAGE_HALF(Bb, n0 + 128 + srow, b + 2, BSL(p, 1)); }
    BAR(); SCHEDB();
    __builtin_amdgcn_s_setprio(1);
    #pragma unroll
    for (int kf = 0; kf < 2; ++kf)
      #pragma unroll
      for (int m = 0; m < 4; ++m)
        #pragma unroll
        for (int n = 2; n < 4; ++n)
          acc[m + 4][n] = __builtin_amdgcn_mfma_f32_16x16x32_bf16(aR[m][kf], bR[n][kf], acc[m + 4][n], 0, 0, 0);
    __builtin_amdgcn_s_setprio(0); SCHEDB();
    if (b + 2 < nkt) { WAITVM4; } else { WAITVM0; }
    BAR();
  }

  // ---- epilogue ----
  if (EPI == 0) {
    #pragma unroll
    for (int m = 0; m < 8; ++m) {
      const int row0 = m0 + wr * 128 + m * 16 + lg * 4;
      #pragma unroll
      for (int n = 0; n < 4; ++n) {
        const int col = n0 + wc * 64 + n * 16 + lr;
        #pragma unroll
        for (int r = 0; r < 4; ++r)
          Cf[(size_t)(row0 + r) * N + col] = acc[m][n][r];
      }
    }
  } else if (EPI == 1) {
    int hh[4], dd[4]; float inv[4]; bool rope[4];
    #pragma unroll
    for (int n = 0; n < 4; ++n) {
      int col = n0 + wc * 64 + n * 16 + lr;
      hh[n] = col / 192;
      dd[n] = col - hh[n] * 192;
      rope[n] = (dd[n] >= 128);
      int i = (dd[n] - 128) >> 1;
      inv[n] = rope[n] ? exp2f(-(float)i * 0.41524101186092f) : 0.f;
    }
    const bool odd = (lr & 1);
    #pragma unroll
    for (int m = 0; m < 8; ++m) {
      const int row0 = m0 + wr * 128 + m * 16 + lg * 4;
      #pragma unroll
      for (int r = 0; r < 4; ++r) {
        const int row = row0 + r;
        const float pv = (float)pos[row];
        #pragma unroll
        for (int n = 0; n < 4; ++n) {
          float v = acc[m][n][r];
          float o = __shfl_xor(v, 1, 64);
          if (rope[n]) {
            float s, c;
            __sincosf(pv * inv[n], &s, &c);
            v = odd ? (o * s + v * c) : (v * c - o * s);
          }
          q_all[((size_t)hh[n] * 2048 + row) * 192 + dd[n]] = f2bf(v);
        }
      }
    }
  } else {
    #pragma unroll
    for (int m = 0; m < 8; ++m) {
      const int row0 = m0 + wr * 128 + m * 16 + lg * 4;
      #pragma unroll
      for (int r = 0; r < 4; ++r) {
        const int row = row0 + r;
        #pragma unroll
        for (int n = 0; n < 4; ++n) {
          const int col = n0 + wc * 64 + n * 16 + lr;
          const int h = col >> 8, dd = col & 255;
          u16 bv = f2bf(acc[m][n][r]);
          if (dd < 128) k_all[((size_t)h * 2048 + row) * 200 + dd] = bv;
          else          v_big[(size_t)row * 4096 + h * 128 + (dd - 128)] = bv;
        }
      }
    }
  }
#undef ASL
#undef BSL
#undef STAGE_HALF
}

// ---------- union launch: LoRA-A GEMM (216 blocks) + big-weight transposes (512 blocks) ----------
// prep blocks: 16896 tiles of 32k x 64n (wqb 0..4607, wkvb 4608..6655, wo 6656..16895), 33/block
#define SLAB2 ((size_t)2048 * 2304)
__global__ __launch_bounds__(512, 2) void gemm_a8p(const u16* __restrict__ A,
                                                   const u16* __restrict__ Bt,
                                                   float* __restrict__ C,
                                                   const float* __restrict__ wqb,  u16* __restrict__ wqb_t,
                                                   const float* __restrict__ wkvb, u16* __restrict__ wkvb_t,
                                                   const float* __restrict__ wo,   u16* __restrict__ wo_t) {
  __shared__ char lds[131072];
  const int b = blockIdx.x;
  if (b < 216) {
    const int z = b / 72;
    const int wg = b - z * 72;
    const int nkt = (z == 2) ? 26 : 27;
    gemm8_body<0>(lds, A, Bt, 2304, 5120, wg, 72, 9, nkt, z * 27,
                  nullptr, nullptr, nullptr, nullptr, C + (size_t)z * SLAB2);
  } else {
    float (*tile)[32][65] = (float (*)[32][65])lds;   // 2 x 8.32 KB
    const int pb = b - 216;
    const int sub = threadIdx.x >> 8, t = threadIdx.x & 255;
    for (int i = 0; i < 17; ++i) {
      const int li = 2 * i + sub;
      const bool ok = (li < 33);
      const float* W = nullptr; u16* Wt = nullptr; int K = 0, N = 0, NT = 1, idx = 0;
      if (ok) {
        int gt = pb * 33 + li;
        if (gt < 4608)      { W = wqb;  Wt = wqb_t;  K = 1536; N = 6144; NT = 96;  idx = gt; }
        else if (gt < 6656) { W = wkvb; Wt = wkvb_t; K = 512;  N = 8192; NT = 128; idx = gt - 4608; }
        else                { W = wo;   Wt = wo_t;   K = 4096; N = 5120; NT = 80;  idx = gt - 6656; }
        const int nt = idx % NT, kt = idx / NT;
        const int n0 = nt * 64, k0 = kt * 32;
        const int r = t >> 3, c8 = (t & 7) << 3;
        const float* src = W + (size_t)(k0 + r) * N + n0 + c8;
        float4 a = *(const float4*)src;
        float4 bb = *(const float4*)(src + 4);
        float* tr = tile[sub][r];
        tr[c8 + 0] = a.x;  tr[c8 + 1] = a.y;  tr[c8 + 2] = a.z;  tr[c8 + 3] = a.w;
        tr[c8 + 4] = bb.x; tr[c8 + 5] = bb.y; tr[c8 + 6] = bb.z; tr[c8 + 7] = bb.w;
      }
      __syncthreads();
      if (ok) {
        const int nt = idx % NT, kt = idx / NT;
        const int n0 = nt * 64, k0 = kt * 32;
        const int n = t >> 2, kg = (t & 3) << 3;
        u16x8 o;
        #pragma unroll
        for (int j = 0; j < 8; ++j) o[j] = f2bf(tile[sub][kg + j][n]);
        *(u16x8*)(Wt + (size_t)(n0 + n) * K + k0 + kg) = o;
      }
      __syncthreads();
    }
  }
}

// ---------- fused q_b + kv_b launch with fused epilogues ----------
__global__ __launch_bounds__(512, 2) void gemm_fused_b(const u16* __restrict__ A1,
                                                       const u16* __restrict__ B1,
                                                       const u16* __restrict__ A2,
                                                       const u16* __restrict__ B2,
                                                       const int* __restrict__ pos,
                                                       u16* __restrict__ q_all,
                                                       u16* __restrict__ k_all,
                                                       u16* __restrict__ v_big) {
  __shared__ char lds[131072];
  if (blockIdx.x < 192)
    gemm8_body<1>(lds, A1, B1, 6144, 1536, blockIdx.x, 192, 24, 24, 0, pos, q_all, nullptr, nullptr, nullptr);
  else
    gemm8_body<2>(lds, A2, B2, 8192, 512, blockIdx.x - 192, 256, 32, 8, 0, pos, nullptr, k_all, v_big, nullptr);
}

// ---------- out-projection (8-phase 256^2, f32 C) ----------
__global__ __launch_bounds__(512, 2) void gemm_out_k(const u16* __restrict__ A,
                                                     const u16* __restrict__ Bt,
                                                     float* __restrict__ C) {
  __shared__ char lds[131072];
  gemm8_body<0>(lds, A, Bt, 5120, 4096, blockIdx.x, 160, 20, 64, 0,
                nullptr, nullptr, nullptr, nullptr, C);
}

// ---------- merged norms: RMSNorm(q) + RMSNorm(kv) + RoPE(k) + k_all rope broadcast ----------
__global__ __launch_bounds__(256) void norm_all(const float* __restrict__ slabs,
                                                const float* __restrict__ wq,
                                                const float* __restrict__ wkv,
                                                const int* __restrict__ pos,
                                                u16* __restrict__ q_c_n,
                                                u16* __restrict__ comp,
                                                u16* __restrict__ k_all) {
  const int row = blockIdx.x, tid = threadIdx.x;
  const float* xr = slabs + (size_t)row * 2304;
  __shared__ float sm[4];
  __shared__ u16 krv[64];

  // ---- q part (cols 0..1535) ----
  float v[6]; float ss = 0.f;
  #pragma unroll
  for (int i = 0; i < 6; ++i) {
    size_t o = tid + i * 256;
    v[i] = xr[o] + xr[o + SLAB2] + xr[o + 2 * SLAB2];
    ss += v[i] * v[i];
  }
  #pragma unroll
  for (int o = 32; o > 0; o >>= 1) ss += __shfl_down(ss, o, 64);
  if ((tid & 63) == 0) sm[tid >> 6] = ss;
  __syncthreads();
  float rsq = rsqrtf((sm[0] + sm[1] + sm[2] + sm[3]) * (1.f / 1536.f) + 1e-6f);
  #pragma unroll
  for (int i = 0; i < 6; ++i)
    q_c_n[(size_t)row * 1536 + tid + i * 256] = f2bf(v[i] * rsq * wq[tid + i * 256]);

  // ---- kv part (cols 1536..2047 norm; 2048..2111 rope) ----
  const float* xk = xr + 1536;
  float v0 = xk[tid] + xk[tid + SLAB2] + xk[tid + 2 * SLAB2];
  size_t o1 = tid + 256;
  float v1 = xk[o1] + xk[o1 + SLAB2] + xk[o1 + 2 * SLAB2];
  float ss2 = v0 * v0 + v1 * v1;
  #pragma unroll
  for (int o = 32; o > 0; o >>= 1) ss2 += __shfl_down(ss2, o, 64);
  __syncthreads();                    // sm reads from q-phase done
  if ((tid & 63) == 0) sm[tid >> 6] = ss2;
  // rope (independent of sum)
  if (tid < 32) {
    float p = (float)pos[row];
    float inv = powf(10000.0f, -(float)(2 * tid) * (1.0f / 64.0f));
    float ang = p * inv;
    float c = cosf(ang), s = sinf(ang);
    size_t e1 = 512 + 2 * tid, e2 = e1 + 1;
    float x1 = xk[e1] + xk[e1 + SLAB2] + xk[e1 + 2 * SLAB2];
    float x2 = xk[e2] + xk[e2 + SLAB2] + xk[e2 + 2 * SLAB2];
    krv[2 * tid]     = f2bf(x1 * c - x2 * s);
    krv[2 * tid + 1] = f2bf(x1 * s + x2 * c);
  }
  __syncthreads();
  float rsk = rsqrtf((sm[0] + sm[1] + sm[2] + sm[3]) * (1.f / 512.f) + 1e-6f);
  comp[(size_t)row * 512 + tid]       = f2bf(v0 * rsk * wkv[tid]);
  comp[(size_t)row * 512 + tid + 256] = f2bf(v1 * rsk * wkv[tid + 256]);

  // broadcast rope to all 32 heads of k_all
  const int h = tid >> 3, j8 = (tid & 7) << 3;
  *(u16x8*)&k_all[((size_t)h * 2048 + row) * 200 + 128 + j8] = *(const u16x8*)&krv[j8];
}

// ---------- V transpose: v_big [2048][4096] -> v_t [h][d][2048] ----------
__global__ __launch_bounds__(256) void v_transpose(const u16* __restrict__ v_big,
                                                   u16* __restrict__ v_t) {
  const int h = blockIdx.x & 31, st = blockIdx.x >> 5, tid = threadIdx.x;
  const int s0 = st * 64;
  __shared__ u16 vs[64][128];
  for (int idx = tid; idx < 4096; idx += 256) {
    int s = idx >> 6, d2 = idx & 63;
    *(u32*)&vs[s][d2 * 2] = *(const u32*)&v_big[(size_t)(s0 + s) * 4096 + h * 128 + d2 * 2];
  }
  __syncthreads();
  const int d = tid >> 1, sh = (tid & 1) * 32;
  u16 tmp[32];
  #pragma unroll
  for (int i = 0; i < 32; ++i) tmp[i] = vs[sh + i][d];
  #pragma unroll
  for (int b = 0; b < 4; ++b) {
    u16x8 o;
    #pragma unroll
    for (int j = 0; j < 8; ++j) o[j] = tmp[b * 8 + j];
    *(u16x8*)(v_t + ((size_t)h * 128 + d) * 2048 + s0 + sh + b * 8) = o;
  }
}

// ---------- flash attention: 8 waves, 128q x 64s tiles, dbuf, swapped-QK, setprio ----------
#define SCL2 0.10412706f
#define THR2 11.5f
__global__ __launch_bounds__(512, 2) void attn_fwd(const u16* __restrict__ q_all,
                                                   const u16* __restrict__ k_all,
                                                   const u16* __restrict__ v_t,
                                                   u16* __restrict__ attnb) {
  __shared__ __align__(16) char lds[106496];
  const int tid = threadIdx.x;
  const int lane = tid & 63, wid = tid >> 6;
  const int lr = lane & 15, lg = lane >> 4;
  const int h = blockIdx.x & 31, bq = blockIdx.x >> 5;

  const char* kh = (const char*)(k_all + (size_t)h * 2048 * 200);
  const char* vh = (const char*)(v_t + (size_t)h * 128 * 2048);
  char* Pw = lds + 88064 + wid * 2304;

  const int nCalls = (wid < 3) ? 6 : 5;
  const char* gp[6]; int cofs[6]; int isK[6];
  #pragma unroll
  for (int ii = 0; ii < 6; ++ii) {
    int i = wid + (ii << 3);
    if (i < 43) {
      int c = (i << 6) + lane;
      cofs[ii] = c << 4;
      if (c < 1600) { gp[ii] = kh + ((size_t)c << 4); isK[ii] = 1; }
      else {
        int cv = c - 1600;
        int row = cv / 9, sub = cv - row * 9;
        gp[ii] = vh + ((size_t)row << 12) + ((sub < 8) ? (sub << 4) : 0);
        isK[ii] = 0;
      }
    } else { gp[ii] = kh; cofs[ii] = 0; isK[ii] = 1; }
  }

#define STAGE(s0_, bOff_)                                                       \
  { int _sk = (s0_) * 400, _sv = (s0_) * 2;                                     \
    _Pragma("unroll")                                                           \
    for (int ii = 0; ii < 6; ++ii)                                              \
      if (ii < nCalls)                                                          \
        gl16(gp[ii] + (isK[ii] ? _sk : _sv), lds + (bOff_) + cofs[ii]); }

#define WAITSTAGE                                                               \
  { if (wid < 3) { asm volatile("s_waitcnt vmcnt(6)" ::: "memory"); }           \
    else        { asm volatile("s_waitcnt vmcnt(5)" ::: "memory"); } }

  const int kRd = lr * 400 + lg * 16;
  const int vRd = lr * 144 + lg * 16;
  const int pRd = lr * 144 + lg * 16;
  const int pWr = lr * 144 + lg * 8;

  #pragma unroll
  for (int half = 0; half < 2; ++half) {
    const int qt = half ? (15 - bq) : bq;
    const int qb0 = qt << 7;
    const int nt = 2 * qt + 2;
    const int qlane = qb0 + wid * 16 + lr;
    const int qwmin = qb0 + wid * 16;

    bf16x8 qf[6];
    const u16* qptr = q_all + ((size_t)h * 2048 + qlane) * 192 + lg * 8;
    #pragma unroll
    for (int kf = 0; kf < 6; ++kf) qf[kf] = *(const bf16x8*)(qptr + kf * 32);

    f32x4 O[8] = {};
    float m = -1e30f, l = 0.f;

    STAGE(0, 0);
    for (int st = 0; st < nt; ++st) {
      const int s0 = st << 6;
      const int bOff = (st & 1) * 44032;
      if (st + 1 < nt) {
        STAGE((st + 1) << 6, ((st + 1) & 1) * 44032);
        WAITSTAGE;
      } else {
        WAITVM0;
      }
      BAR();

      const bool active = (s0 <= qwmin + 15);
      if (active) {
        const char* Kb = lds + bOff;
        const char* Vb = lds + bOff + 25600;

        f32x4 S[4];
        __builtin_amdgcn_s_setprio(1);
        #pragma unroll
        for (int sb = 0; sb < 4; ++sb) {
          f32x4 a = {};
          #pragma unroll
          for (int kf = 0; kf < 6; ++kf) {
            bf16x8 kfr = *(const bf16x8*)(Kb + kRd + sb * 6400 + kf * 64);
            a = __builtin_amdgcn_mfma_f32_16x16x32_bf16(kfr, qf[kf], a, 0, 0, 0);
          }
          S[sb] = a;
        }
        __builtin_amdgcn_s_setprio(0);

        if (s0 + 63 > qwmin) {
          const int kb0 = s0 + lg * 4;
          #pragma unroll
          for (int sb = 0; sb < 4; ++sb)
            #pragma unroll
            for (int r = 0; r < 4; ++r) {
              int k = kb0 + sb * 16 + r;
              S[sb][r] = (k > qlane) ? -1e30f : S[sb][r] * SCL2;
            }
        } else {
          #pragma unroll
          for (int sb = 0; sb < 4; ++sb)
            #pragma unroll
            for (int r = 0; r < 4; ++r) S[sb][r] *= SCL2;
        }

        float mx = S[0][0];
        #pragma unroll
        for (int sb = 0; sb < 4; ++sb)
          #pragma unroll
          for (int r = 0; r < 4; ++r) mx = fmaxf(mx, S[sb][r]);
        mx = fmaxf(mx, __shfl_xor(mx, 16, 64));
        mx = fmaxf(mx, __shfl_xor(mx, 32, 64));

        const bool skip = __all(mx <= m + THR2);
        float alpha = 1.f;
        if (!skip) { float mn = fmaxf(m, mx); alpha = exp2f(m - mn); m = mn; }

        float ps = 0.f;
        #pragma unroll
        for (int sb = 0; sb < 4; ++sb)
          #pragma unroll
          for (int r = 0; r < 4; ++r) {
            float pv = exp2f(S[sb][r] - m);
            S[sb][r] = pv;
            ps += pv;
          }
        ps += __shfl_xor(ps, 16, 64);
        ps += __shfl_xor(ps, 32, 64);
        l = l * alpha + ps;

        if (!skip) {
          float aO[4];
          #pragma unroll
          for (int r = 0; r < 4; ++r) aO[r] = __shfl(alpha, lg * 4 + r, 64);
          #pragma unroll
          for (int nb = 0; nb < 8; ++nb)
            #pragma unroll
            for (int r = 0; r < 4; ++r) O[nb][r] *= aO[r];
        }

        #pragma unroll
        for (int sb = 0; sb < 4; ++sb) {
          u32 p01, p23;
          asm("v_cvt_pk_bf16_f32 %0, %1, %2" : "=v"(p01) : "v"(S[sb][0]), "v"(S[sb][1]));
          asm("v_cvt_pk_bf16_f32 %0, %1, %2" : "=v"(p23) : "v"(S[sb][2]), "v"(S[sb][3]));
          *(uint2*)(Pw + pWr + sb * 32) = make_uint2(p01, p23);
        }

        __builtin_amdgcn_s_setprio(1);
        #pragma unroll
        for (int k2 = 0; k2 < 2; ++k2) {
          bf16x8 pa = *(const bf16x8*)(Pw + pRd + k2 * 64);
          #pragma unroll
          for (int nb = 0; nb < 8; ++nb) {
            bf16x8 vf = *(const bf16x8*)(Vb + vRd + nb * 2304 + k2 * 64);
            O[nb] = __builtin_amdgcn_mfma_f32_16x16x32_bf16(pa, vf, O[nb], 0, 0, 0);
          }
        }
        __builtin_amdgcn_s_setprio(0);
      }
      BAR();
    }

    float rv[4];
    #pragma unroll
    for (int r = 0; r < 4; ++r) rv[r] = 1.f / __shfl(l, lg * 4 + r, 64);
    #pragma unroll
    for (int nb = 0; nb < 8; ++nb) {
      const int col = h * 128 + nb * 16 + lr;
      #pragma unroll
      for (int r = 0; r < 4; ++r)
        attnb[(size_t)(qb0 + wid * 16 + lg * 4 + r) * 4096 + col] = f2bf(O[nb][r] * rv[r]);
    }
  }
#undef STAGE
#undef WAITSTAGE
}

// ---------- host ----------
extern "C" void kernel_launch(void* const* d_in, const int* in_sizes, int n_in,
                              void* d_out, int out_size, void* d_ws, size_t ws_size,
                              hipStream_t stream) {
  const int*   positions = (const int*)d_in[0];
  const float* hidden    = (const float*)d_in[1];
  const float* w_q_a     = (const float*)d_in[2];
  const float* q_a_norm  = (const float*)d_in[3];
  const float* w_q_b     = (const float*)d_in[4];
  const float* w_kv_a    = (const float*)d_in[5];
  const float* kv_a_norm = (const float*)d_in[6];
  const float* w_kv_b    = (const float*)d_in[7];
  const float* w_o       = (const float*)d_in[8];
  float* out = (float*)d_out;
  char*  ws  = (char*)d_ws;

  // layout (bytes), total 203,948,032 (same as R9)
  u16* hs_bf  = (u16*)(ws + 0);
  u16* attnb  = (u16*)(ws + 0);
  u16* wab_t  = (u16*)(ws + 20971520);
  u16* q_c_n  = (u16*)(ws + 20971520);
  u16* comp   = (u16*)(ws + 27262976);
  u16* wqb_t  = (u16*)(ws + 44564480);
  u16* wkvb_t = (u16*)(ws + 63438848);
  u16* wo_t   = (u16*)(ws + 71827456);
  float* slabs = (float*)(ws + 113770496);
  u16* q_all  = (u16*)(ws + 113770496);
  u16* k_all  = (u16*)(ws + 138936320);
  u16* v_big  = (u16*)(ws + 170393600);
  u16* v_t    = (u16*)(ws + 187170816);

  // 1) stage-1 prep: cvt(hidden) + wqa/wkva transpose + pad zero
  prep_a<<<6400, 256, 0, stream>>>(hidden, hs_bf, w_q_a, w_kv_a, wab_t);

  // 2) union: LoRA-A GEMM (216 blocks) + wqb/wkvb/wo transposes (512 blocks)
  gemm_a8p<<<728, 512, 0, stream>>>(hs_bf, wab_t, slabs,
                                    w_q_b, wqb_t, w_kv_b, wkvb_t, w_o, wo_t);

  // 3) merged norms (+rope broadcast into k_all)
  norm_all<<<2048, 256, 0, stream>>>(slabs, q_a_norm, kv_a_norm, positions,
                                     q_c_n, comp, k_all);

  // 4) fused q_b + kv_b with layout/rope epilogues
  gemm_fused_b<<<448, 512, 0, stream>>>(q_c_n, wqb_t, comp, wkvb_t, positions,
                                        q_all, k_all, v_big);

  // 5) V transpose
  v_transpose<<<1024, 256, 0, stream>>>(v_big, v_t);

  // 6) attention
  attn_fwd<<<256, 512, 0, stream>>>(q_all, k_all, v_t, attnb);

  // 7) output projection (8-phase 256^2, 160 blocks)
  gemm_out_k<<<160, 512, 0, stream>>>(attnb, wo_t, out);
}

// Round 11
// 396.406 us; speedup vs baseline: 1.0490x; 1.0490x over previous
//
#include <hip/hip_runtime.h>

typedef unsigned short u16;
typedef unsigned int   u32;
typedef __bf16 bf16x8 __attribute__((ext_vector_type(8)));
typedef float  f32x4  __attribute__((ext_vector_type(4)));
typedef u16    u16x4  __attribute__((ext_vector_type(4)));
typedef u16    u16x8  __attribute__((ext_vector_type(8)));

// ---------- helpers ----------
__device__ __forceinline__ u16 f2bf(float f) {
  u32 u = __float_as_uint(f);
  u32 r = u + 0x7fffu + ((u >> 16) & 1u);   // RTNE
  return (u16)(r >> 16);
}

__device__ __forceinline__ void gl16(const void* g, void* l) {
  __builtin_amdgcn_global_load_lds((__attribute__((address_space(1))) void*)(g),
                                   (__attribute__((address_space(3))) void*)(l),
                                   16, 0, 0);
}

#define WAITVM4  asm volatile("s_waitcnt vmcnt(4)" ::: "memory")
#define WAITVM0  asm volatile("s_waitcnt vmcnt(0)" ::: "memory")
#define WAITLG0  asm volatile("s_waitcnt lgkmcnt(0)" ::: "memory")
#define BAR()    asm volatile("s_barrier" ::: "memory")
#define SCHEDB() __builtin_amdgcn_sched_barrier(0)

// ---------- prep_w: cvt(hidden) + ALL weight transposes + pad zero (separate, high-occ) ----------
__device__ __forceinline__ void tr_tile(const float* __restrict__ W, u16* __restrict__ Wt,
                                        int K, int N, int NT, int idx, float (*tile)[65]) {
  const int tid = threadIdx.x;
  const int nt = idx % NT, kt = idx / NT;
  const int n0 = nt * 64, k0 = kt * 32;
  {
    const int r = tid >> 3, c8 = (tid & 7) << 3;
    const float* src = W + (size_t)(k0 + r) * N + n0 + c8;
    float4 a = *(const float4*)src;
    float4 b = *(const float4*)(src + 4);
    tile[r][c8 + 0] = a.x; tile[r][c8 + 1] = a.y; tile[r][c8 + 2] = a.z; tile[r][c8 + 3] = a.w;
    tile[r][c8 + 4] = b.x; tile[r][c8 + 5] = b.y; tile[r][c8 + 6] = b.z; tile[r][c8 + 7] = b.w;
  }
  __syncthreads();
  const int n = tid >> 2, kg = (tid & 3) << 3;
  u16x8 o;
  #pragma unroll
  for (int j = 0; j < 8; ++j) o[j] = f2bf(tile[kg + j][n]);
  *(u16x8*)(Wt + (size_t)(n0 + n) * K + k0 + kg) = o;
}

// wab_t: merged [2304][5120]: rows 0..1535 = wqa^T, 1536..2111 = wkva^T, 2112..2303 = 0
__global__ __launch_bounds__(256) void prep_w(const float* __restrict__ hidden, u16* __restrict__ hs_bf,
                                              const float* __restrict__ wqa,
                                              const float* __restrict__ wkva, u16* __restrict__ wab_t,
                                              const float* __restrict__ wqb,  u16* __restrict__ wqb_t,
                                              const float* __restrict__ wkvb, u16* __restrict__ wkvb_t,
                                              const float* __restrict__ wo,   u16* __restrict__ wo_t) {
  __shared__ float tile[32][65];
  const int b = blockIdx.x, tid = threadIdx.x;
  if (b < 640) {                       // cvt: hidden [2048][5120] f32 -> bf16
    const float4* xin = (const float4*)hidden;
    #pragma unroll
    for (int j = 0; j < 8; ++j) {
      int u = b * 2048 + j * 256 + tid;
      float4 a = xin[u * 2], c = xin[u * 2 + 1];
      u16x8 o;
      o[0] = f2bf(a.x); o[1] = f2bf(a.y); o[2] = f2bf(a.z); o[3] = f2bf(a.w);
      o[4] = f2bf(c.x); o[5] = f2bf(c.y); o[6] = f2bf(c.z); o[7] = f2bf(c.w);
      *(u16x8*)(hs_bf + (size_t)u * 8) = o;
    }
  } else if (b < 4480) {               // w_q_a [5120][1536] -> wab_t rows 0..1535
    tr_tile(wqa, wab_t, 5120, 1536, 24, b - 640, tile);
  } else if (b < 5920) {               // w_kv_a [5120][576] -> wab_t rows 1536..2111
    tr_tile(wkva, wab_t + (size_t)1536 * 5120, 5120, 576, 9, b - 4480, tile);
  } else if (b < 10528) {              // w_q_b [1536][6144]
    tr_tile(wqb, wqb_t, 1536, 6144, 96, b - 5920, tile);
  } else if (b < 12576) {              // w_kv_b [512][8192]
    tr_tile(wkvb, wkvb_t, 512, 8192, 128, b - 10528, tile);
  } else if (b < 22816) {              // w_o [4096][5120]
    tr_tile(wo, wo_t, 4096, 5120, 80, b - 12576, tile);
  } else {                             // zero wab_t rows 2112..2303 (480 blocks)
    size_t off = (size_t)(b - 22816) * 4096 + tid * 16;
    u16x8 z = {};
    *(u16x8*)((char*)wab_t + (size_t)2112 * 5120 * 2 + off) = z;
  }
}

// ---------- shared 8-phase 256x256 GEMM body ----------
// EPI=0: f32 C   EPI=1: q->rope->q_all   EPI=2: kv->k_all/v_big
template<int EPI>
__device__ __forceinline__ void gemm8_body(char* lds,
                                           const u16* __restrict__ A,
                                           const u16* __restrict__ Bt,
                                           int N, int K, int wg, int nwg, int nbx,
                                           int nkt, int kt0,
                                           const int* __restrict__ pos,
                                           u16* __restrict__ q_all,
                                           u16* __restrict__ k_all,
                                           u16* __restrict__ v_big,
                                           float* __restrict__ Cf) {
  const int tid = threadIdx.x;
  const int lane = tid & 63, wid = tid >> 6;
  const int wr = wid >> 2, wc = wid & 3;
  const int lr = lane & 15, lg = lane >> 4;

  const int swz = ((nwg & 7) == 0) ? ((wg & 7) * (nwg >> 3) + (wg >> 3)) : wg;
  const int bx = swz % nbx, by = swz / nbx;
  const int m0 = by << 8, n0 = bx << 8;

  const size_t rs = (size_t)K << 1;
  const char* Ab = (const char*)A;
  const char* Bb = (const char*)Bt;

  const int sofs = tid << 4;
  const int srow = sofs >> 7;
  const int scol = ((((sofs >> 4) & 7) ^ (srow & 7)) << 4);

  const int axor = lr & 7;
  const int sx0 = (lg ^ axor) << 4;
  const int sx1 = ((4 | lg) ^ axor) << 4;
  const int bcolbase = (wc & 1) << 13;

  f32x4 acc[8][4] = {};

#define ASL(p,h) ((((p) << 1) | (h)) << 14)
#define BSL(p,h) (65536 + ((((p) << 1) | (h)) << 14))
#define STAGE_HALF(gb, grow0, kt, slot)                                              \
  { const char* _s = (gb) + (size_t)(grow0) * rs + ((size_t)((kt) + kt0) << 7) + scol; \
    gl16(_s, lds + (slot) + sofs);                                                   \
    gl16(_s + (rs << 6), lds + (slot) + sofs + 8192); }

  STAGE_HALF(Ab, m0 + srow,       0, ASL(0,0));
  STAGE_HALF(Ab, m0 + 128 + srow, 0, ASL(0,1));
  STAGE_HALF(Bb, n0 + srow,       0, BSL(0,0));
  STAGE_HALF(Bb, n0 + 128 + srow, 0, BSL(0,1));
  if (nkt > 1) {
    STAGE_HALF(Bb, n0 + srow,       1, BSL(1,0));
    STAGE_HALF(Bb, n0 + 128 + srow, 1, BSL(1,1));
    WAITVM4;
  } else {
    WAITVM0;
  }
  BAR();

  for (int b = 0; b < nkt; ++b) {
    const int p = b & 1;
    const int abase = ASL(p, wr);
    const int bbase = BSL(p, (wc >> 1)) + bcolbase;
    bf16x8 aR[4][2], bR[4][2];

    #pragma unroll
    for (int m = 0; m < 4; ++m) {
      aR[m][0] = *(const bf16x8*)(lds + abase + (m * 16 + lr) * 128 + sx0);
      aR[m][1] = *(const bf16x8*)(lds + abase + (m * 16 + lr) * 128 + sx1);
    }
    #pragma unroll
    for (int n = 0; n < 2; ++n) {
      bR[n][0] = *(const bf16x8*)(lds + bbase + (n * 16 + lr) * 128 + sx0);
      bR[n][1] = *(const bf16x8*)(lds + bbase + (n * 16 + lr) * 128 + sx1);
    }
    if (b + 1 < nkt) { STAGE_HALF(Ab, m0 + srow, b + 1, ASL((b + 1) & 1, 0)); }
    BAR(); WAITLG0; SCHEDB();
    __builtin_amdgcn_s_setprio(1);
    #pragma unroll
    for (int kf = 0; kf < 2; ++kf)
      #pragma unroll
      for (int m = 0; m < 4; ++m)
        #pragma unroll
        for (int n = 0; n < 2; ++n)
          acc[m][n] = __builtin_amdgcn_mfma_f32_16x16x32_bf16(aR[m][kf], bR[n][kf], acc[m][n], 0, 0, 0);
    __builtin_amdgcn_s_setprio(0); SCHEDB();
    BAR();

    #pragma unroll
    for (int n = 2; n < 4; ++n) {
      bR[n][0] = *(const bf16x8*)(lds + bbase + (n * 16 + lr) * 128 + sx0);
      bR[n][1] = *(const bf16x8*)(lds + bbase + (n * 16 + lr) * 128 + sx1);
    }
    if (b + 1 < nkt) { STAGE_HALF(Ab, m0 + 128 + srow, b + 1, ASL((b + 1) & 1, 1)); }
    BAR(); WAITLG0; SCHEDB();
    __builtin_amdgcn_s_setprio(1);
    #pragma unroll
    for (int kf = 0; kf < 2; ++kf)
      #pragma unroll
      for (int m = 0; m < 4; ++m)
        #pragma unroll
        for (int n = 2; n < 4; ++n)
          acc[m][n] = __builtin_amdgcn_mfma_f32_16x16x32_bf16(aR[m][kf], bR[n][kf], acc[m][n], 0, 0, 0);
    __builtin_amdgcn_s_setprio(0); SCHEDB();
    BAR();

    #pragma unroll
    for (int m = 0; m < 4; ++m) {
      aR[m][0] = *(const bf16x8*)(lds + abase + ((m + 4) * 16 + lr) * 128 + sx0);
      aR[m][1] = *(const bf16x8*)(lds + abase + ((m + 4) * 16 + lr) * 128 + sx1);
    }
    if (b + 2 < nkt) { STAGE_HALF(Bb, n0 + srow, b + 2, BSL(p, 0)); }
    BAR(); WAITLG0; SCHEDB();
    __builtin_amdgcn_s_setprio(1);
    #pragma unroll
    for (int kf = 0; kf < 2; ++kf)
      #pragma unroll
      for (int m = 0; m < 4; ++m)
        #pragma unroll
        for (int n = 0; n < 2; ++n)
          acc[m + 4][n] = __builtin_amdgcn_mfma_f32_16x16x32_bf16(aR[m][kf], bR[n][kf], acc[m + 4][n], 0, 0, 0);
    __builtin_amdgcn_s_setprio(0); SCHEDB();
    BAR();

    if (b + 2 < nkt) { STAGE_HALF(Bb, n0 + 128 + srow, b + 2, BSL(p, 1)); }
    BAR(); SCHEDB();
    __builtin_amdgcn_s_setprio(1);
    #pragma unroll
    for (int kf = 0; kf < 2; ++kf)
      #pragma unroll
      for (int m = 0; m < 4; ++m)
        #pragma unroll
        for (int n = 2; n < 4; ++n)
          acc[m + 4][n] = __builtin_amdgcn_mfma_f32_16x16x32_bf16(aR[m][kf], bR[n][kf], acc[m + 4][n], 0, 0, 0);
    __builtin_amdgcn_s_setprio(0); SCHEDB();
    if (b + 2 < nkt) { WAITVM4; } else { WAITVM0; }
    BAR();
  }

  // ---- epilogue ----
  if (EPI == 0) {
    #pragma unroll
    for (int m = 0; m < 8; ++m) {
      const int row0 = m0 + wr * 128 + m * 16 + lg * 4;
      #pragma unroll
      for (int n = 0; n < 4; ++n) {
        const int col = n0 + wc * 64 + n * 16 + lr;
        #pragma unroll
        for (int r = 0; r < 4; ++r)
          Cf[(size_t)(row0 + r) * N + col] = acc[m][n][r];
      }
    }
  } else if (EPI == 1) {
    int hh[4], dd[4]; float inv[4]; bool rope[4];
    #pragma unroll
    for (int n = 0; n < 4; ++n) {
      int col = n0 + wc * 64 + n * 16 + lr;
      hh[n] = col / 192;
      dd[n] = col - hh[n] * 192;
      rope[n] = (dd[n] >= 128);
      int i = (dd[n] - 128) >> 1;
      inv[n] = rope[n] ? exp2f(-(float)i * 0.41524101186092f) : 0.f;
    }
    const bool odd = (lr & 1);
    #pragma unroll
    for (int m = 0; m < 8; ++m) {
      const int row0 = m0 + wr * 128 + m * 16 + lg * 4;
      #pragma unroll
      for (int r = 0; r < 4; ++r) {
        const int row = row0 + r;
        const float pv = (float)pos[row];
        #pragma unroll
        for (int n = 0; n < 4; ++n) {
          float v = acc[m][n][r];
          float o = __shfl_xor(v, 1, 64);
          if (rope[n]) {
            float s, c;
            __sincosf(pv * inv[n], &s, &c);
            v = odd ? (o * s + v * c) : (v * c - o * s);
          }
          q_all[((size_t)hh[n] * 2048 + row) * 192 + dd[n]] = f2bf(v);
        }
      }
    }
  } else {
    #pragma unroll
    for (int m = 0; m < 8; ++m) {
      const int row0 = m0 + wr * 128 + m * 16 + lg * 4;
      #pragma unroll
      for (int r = 0; r < 4; ++r) {
        const int row = row0 + r;
        #pragma unroll
        for (int n = 0; n < 4; ++n) {
          const int col = n0 + wc * 64 + n * 16 + lr;
          const int h = col >> 8, dd = col & 255;
          u16 bv = f2bf(acc[m][n][r]);
          if (dd < 128) k_all[((size_t)h * 2048 + row) * 200 + dd] = bv;
          else          v_big[(size_t)row * 4096 + h * 128 + (dd - 128)] = bv;
        }
      }
    }
  }
#undef ASL
#undef BSL
#undef STAGE_HALF
}

// ---------- LoRA-A GEMM: 8-phase 256^2, Npad=2304, split-K=3 into slabs ----------
#define SLAB2 ((size_t)2048 * 2304)
__global__ __launch_bounds__(512, 2) void gemm_a8(const u16* __restrict__ A,
                                                  const u16* __restrict__ Bt,
                                                  float* __restrict__ C) {
  __shared__ char lds[131072];
  const int z = blockIdx.x / 72;                 // 0..2
  const int wg = blockIdx.x - z * 72;
  const int nkt = (z == 2) ? 26 : 27;            // 27+27+26 = 80 k-tiles (K=5120)
  gemm8_body<0>(lds, A, Bt, 2304, 5120, wg, 72, 9, nkt, z * 27,
                nullptr, nullptr, nullptr, nullptr, C + (size_t)z * SLAB2);
}

// ---------- fused q_b + kv_b launch with fused epilogues ----------
__global__ __launch_bounds__(512, 2) void gemm_fused_b(const u16* __restrict__ A1,
                                                       const u16* __restrict__ B1,
                                                       const u16* __restrict__ A2,
                                                       const u16* __restrict__ B2,
                                                       const int* __restrict__ pos,
                                                       u16* __restrict__ q_all,
                                                       u16* __restrict__ k_all,
                                                       u16* __restrict__ v_big) {
  __shared__ char lds[131072];
  if (blockIdx.x < 192)
    gemm8_body<1>(lds, A1, B1, 6144, 1536, blockIdx.x, 192, 24, 24, 0, pos, q_all, nullptr, nullptr, nullptr);
  else
    gemm8_body<2>(lds, A2, B2, 8192, 512, blockIdx.x - 192, 256, 32, 8, 0, pos, nullptr, k_all, v_big, nullptr);
}

// ---------- out-projection (8-phase 256^2, f32 C) ----------
__global__ __launch_bounds__(512, 2) void gemm_out_k(const u16* __restrict__ A,
                                                     const u16* __restrict__ Bt,
                                                     float* __restrict__ C) {
  __shared__ char lds[131072];
  gemm8_body<0>(lds, A, Bt, 5120, 4096, blockIdx.x, 160, 20, 64, 0,
                nullptr, nullptr, nullptr, nullptr, C);
}

// ---------- merged norms: RMSNorm(q) + RMSNorm(kv) + RoPE(k) + k_all rope broadcast ----------
__global__ __launch_bounds__(256) void norm_all(const float* __restrict__ slabs,
                                                const float* __restrict__ wq,
                                                const float* __restrict__ wkv,
                                                const int* __restrict__ pos,
                                                u16* __restrict__ q_c_n,
                                                u16* __restrict__ comp,
                                                u16* __restrict__ k_all) {
  const int row = blockIdx.x, tid = threadIdx.x;
  const float* xr = slabs + (size_t)row * 2304;
  __shared__ float sm[4];
  __shared__ u16 krv[64];

  // ---- q part (cols 0..1535) ----
  float v[6]; float ss = 0.f;
  #pragma unroll
  for (int i = 0; i < 6; ++i) {
    size_t o = tid + i * 256;
    v[i] = xr[o] + xr[o + SLAB2] + xr[o + 2 * SLAB2];
    ss += v[i] * v[i];
  }
  #pragma unroll
  for (int o = 32; o > 0; o >>= 1) ss += __shfl_down(ss, o, 64);
  if ((tid & 63) == 0) sm[tid >> 6] = ss;
  __syncthreads();
  float rsq = rsqrtf((sm[0] + sm[1] + sm[2] + sm[3]) * (1.f / 1536.f) + 1e-6f);
  #pragma unroll
  for (int i = 0; i < 6; ++i)
    q_c_n[(size_t)row * 1536 + tid + i * 256] = f2bf(v[i] * rsq * wq[tid + i * 256]);

  // ---- kv part (cols 1536..2047 norm; 2048..2111 rope) ----
  const float* xk = xr + 1536;
  float v0 = xk[tid] + xk[tid + SLAB2] + xk[tid + 2 * SLAB2];
  size_t o1 = tid + 256;
  float v1 = xk[o1] + xk[o1 + SLAB2] + xk[o1 + 2 * SLAB2];
  float ss2 = v0 * v0 + v1 * v1;
  #pragma unroll
  for (int o = 32; o > 0; o >>= 1) ss2 += __shfl_down(ss2, o, 64);
  __syncthreads();                    // all sm reads from q-phase done
  if ((tid & 63) == 0) sm[tid >> 6] = ss2;
  if (tid < 32) {
    float p = (float)pos[row];
    float inv = powf(10000.0f, -(float)(2 * tid) * (1.0f / 64.0f));
    float ang = p * inv;
    float c = cosf(ang), s = sinf(ang);
    size_t e1 = 512 + 2 * tid, e2 = e1 + 1;
    float x1 = xk[e1] + xk[e1 + SLAB2] + xk[e1 + 2 * SLAB2];
    float x2 = xk[e2] + xk[e2 + SLAB2] + xk[e2 + 2 * SLAB2];
    krv[2 * tid]     = f2bf(x1 * c - x2 * s);
    krv[2 * tid + 1] = f2bf(x1 * s + x2 * c);
  }
  __syncthreads();
  float rsk = rsqrtf((sm[0] + sm[1] + sm[2] + sm[3]) * (1.f / 512.f) + 1e-6f);
  comp[(size_t)row * 512 + tid]       = f2bf(v0 * rsk * wkv[tid]);
  comp[(size_t)row * 512 + tid + 256] = f2bf(v1 * rsk * wkv[tid + 256]);

  const int h = tid >> 3, j8 = (tid & 7) << 3;
  *(u16x8*)&k_all[((size_t)h * 2048 + row) * 200 + 128 + j8] = *(const u16x8*)&krv[j8];
}

// ---------- V transpose: v_big [2048][4096] -> v_t [h][d][2048] ----------
__global__ __launch_bounds__(256) void v_transpose(const u16* __restrict__ v_big,
                                                   u16* __restrict__ v_t) {
  const int h = blockIdx.x & 31, st = blockIdx.x >> 5, tid = threadIdx.x;
  const int s0 = st * 64;
  __shared__ u16 vs[64][128];
  for (int idx = tid; idx < 4096; idx += 256) {
    int s = idx >> 6, d2 = idx & 63;
    *(u32*)&vs[s][d2 * 2] = *(const u32*)&v_big[(size_t)(s0 + s) * 4096 + h * 128 + d2 * 2];
  }
  __syncthreads();
  const int d = tid >> 1, sh = (tid & 1) * 32;
  u16 tmp[32];
  #pragma unroll
  for (int i = 0; i < 32; ++i) tmp[i] = vs[sh + i][d];
  #pragma unroll
  for (int b = 0; b < 4; ++b) {
    u16x8 o;
    #pragma unroll
    for (int j = 0; j < 8; ++j) o[j] = tmp[b * 8 + j];
    *(u16x8*)(v_t + ((size_t)h * 128 + d) * 2048 + s0 + sh + b * 8) = o;
  }
}

// ---------- flash attention: 8 waves, 128q x 64s tiles, dbuf, swapped-QK, setprio ----------
#define SCL2 0.10412706f
#define THR2 11.5f
__global__ __launch_bounds__(512, 2) void attn_fwd(const u16* __restrict__ q_all,
                                                   const u16* __restrict__ k_all,
                                                   const u16* __restrict__ v_t,
                                                   u16* __restrict__ attnb) {
  __shared__ __align__(16) char lds[106496];
  const int tid = threadIdx.x;
  const int lane = tid & 63, wid = tid >> 6;
  const int lr = lane & 15, lg = lane >> 4;
  const int h = blockIdx.x & 31, bq = blockIdx.x >> 5;

  const char* kh = (const char*)(k_all + (size_t)h * 2048 * 200);
  const char* vh = (const char*)(v_t + (size_t)h * 128 * 2048);
  char* Pw = lds + 88064 + wid * 2304;

  const int nCalls = (wid < 3) ? 6 : 5;
  const char* gp[6]; int cofs[6]; int isK[6];
  #pragma unroll
  for (int ii = 0; ii < 6; ++ii) {
    int i = wid + (ii << 3);
    if (i < 43) {
      int c = (i << 6) + lane;
      cofs[ii] = c << 4;
      if (c < 1600) { gp[ii] = kh + ((size_t)c << 4); isK[ii] = 1; }
      else {
        int cv = c - 1600;
        int row = cv / 9, sub = cv - row * 9;
        gp[ii] = vh + ((size_t)row << 12) + ((sub < 8) ? (sub << 4) : 0);
        isK[ii] = 0;
      }
    } else { gp[ii] = kh; cofs[ii] = 0; isK[ii] = 1; }
  }

#define STAGE(s0_, bOff_)                                                       \
  { int _sk = (s0_) * 400, _sv = (s0_) * 2;                                     \
    _Pragma("unroll")                                                           \
    for (int ii = 0; ii < 6; ++ii)                                              \
      if (ii < nCalls)                                                          \
        gl16(gp[ii] + (isK[ii] ? _sk : _sv), lds + (bOff_) + cofs[ii]); }

#define WAITSTAGE                                                               \
  { if (wid < 3) { asm volatile("s_waitcnt vmcnt(6)" ::: "memory"); }           \
    else        { asm volatile("s_waitcnt vmcnt(5)" ::: "memory"); } }

  const int kRd = lr * 400 + lg * 16;
  const int vRd = lr * 144 + lg * 16;
  const int pRd = lr * 144 + lg * 16;
  const int pWr = lr * 144 + lg * 8;

  #pragma unroll
  for (int half = 0; half < 2; ++half) {
    const int qt = half ? (15 - bq) : bq;
    const int qb0 = qt << 7;
    const int nt = 2 * qt + 2;
    const int qlane = qb0 + wid * 16 + lr;
    const int qwmin = qb0 + wid * 16;

    bf16x8 qf[6];
    const u16* qptr = q_all + ((size_t)h * 2048 + qlane) * 192 + lg * 8;
    #pragma unroll
    for (int kf = 0; kf < 6; ++kf) qf[kf] = *(const bf16x8*)(qptr + kf * 32);

    f32x4 O[8] = {};
    float m = -1e30f, l = 0.f;

    STAGE(0, 0);
    for (int st = 0; st < nt; ++st) {
      const int s0 = st << 6;
      const int bOff = (st & 1) * 44032;
      if (st + 1 < nt) {
        STAGE((st + 1) << 6, ((st + 1) & 1) * 44032);
        WAITSTAGE;
      } else {
        WAITVM0;
      }
      BAR();

      const bool active = (s0 <= qwmin + 15);
      if (active) {
        const char* Kb = lds + bOff;
        const char* Vb = lds + bOff + 25600;

        f32x4 S[4];
        __builtin_amdgcn_s_setprio(1);
        #pragma unroll
        for (int sb = 0; sb < 4; ++sb) {
          f32x4 a = {};
          #pragma unroll
          for (int kf = 0; kf < 6; ++kf) {
            bf16x8 kfr = *(const bf16x8*)(Kb + kRd + sb * 6400 + kf * 64);
            a = __builtin_amdgcn_mfma_f32_16x16x32_bf16(kfr, qf[kf], a, 0, 0, 0);
          }
          S[sb] = a;
        }
        __builtin_amdgcn_s_setprio(0);

        if (s0 + 63 > qwmin) {
          const int kb0 = s0 + lg * 4;
          #pragma unroll
          for (int sb = 0; sb < 4; ++sb)
            #pragma unroll
            for (int r = 0; r < 4; ++r) {
              int k = kb0 + sb * 16 + r;
              S[sb][r] = (k > qlane) ? -1e30f : S[sb][r] * SCL2;
            }
        } else {
          #pragma unroll
          for (int sb = 0; sb < 4; ++sb)
            #pragma unroll
            for (int r = 0; r < 4; ++r) S[sb][r] *= SCL2;
        }

        float mx = S[0][0];
        #pragma unroll
        for (int sb = 0; sb < 4; ++sb)
          #pragma unroll
          for (int r = 0; r < 4; ++r) mx = fmaxf(mx, S[sb][r]);
        mx = fmaxf(mx, __shfl_xor(mx, 16, 64));
        mx = fmaxf(mx, __shfl_xor(mx, 32, 64));

        const bool skip = __all(mx <= m + THR2);
        float alpha = 1.f;
        if (!skip) { float mn = fmaxf(m, mx); alpha = exp2f(m - mn); m = mn; }

        float ps = 0.f;
        #pragma unroll
        for (int sb = 0; sb < 4; ++sb)
          #pragma unroll
          for (int r = 0; r < 4; ++r) {
            float pv = exp2f(S[sb][r] - m);
            S[sb][r] = pv;
            ps += pv;
          }
        ps += __shfl_xor(ps, 16, 64);
        ps += __shfl_xor(ps, 32, 64);
        l = l * alpha + ps;

        if (!skip) {
          float aO[4];
          #pragma unroll
          for (int r = 0; r < 4; ++r) aO[r] = __shfl(alpha, lg * 4 + r, 64);
          #pragma unroll
          for (int nb = 0; nb < 8; ++nb)
            #pragma unroll
            for (int r = 0; r < 4; ++r) O[nb][r] *= aO[r];
        }

        #pragma unroll
        for (int sb = 0; sb < 4; ++sb) {
          u32 p01, p23;
          asm("v_cvt_pk_bf16_f32 %0, %1, %2" : "=v"(p01) : "v"(S[sb][0]), "v"(S[sb][1]));
          asm("v_cvt_pk_bf16_f32 %0, %1, %2" : "=v"(p23) : "v"(S[sb][2]), "v"(S[sb][3]));
          *(uint2*)(Pw + pWr + sb * 32) = make_uint2(p01, p23);
        }

        __builtin_amdgcn_s_setprio(1);
        #pragma unroll
        for (int k2 = 0; k2 < 2; ++k2) {
          bf16x8 pa = *(const bf16x8*)(Pw + pRd + k2 * 64);
          #pragma unroll
          for (int nb = 0; nb < 8; ++nb) {
            bf16x8 vf = *(const bf16x8*)(Vb + vRd + nb * 2304 + k2 * 64);
            O[nb] = __builtin_amdgcn_mfma_f32_16x16x32_bf16(pa, vf, O[nb], 0, 0, 0);
          }
        }
        __builtin_amdgcn_s_setprio(0);
      }
      BAR();
    }

    float rv[4];
    #pragma unroll
    for (int r = 0; r < 4; ++r) rv[r] = 1.f / __shfl(l, lg * 4 + r, 64);
    #pragma unroll
    for (int nb = 0; nb < 8; ++nb) {
      const int col = h * 128 + nb * 16 + lr;
      #pragma unroll
      for (int r = 0; r < 4; ++r)
        attnb[(size_t)(qb0 + wid * 16 + lg * 4 + r) * 4096 + col] = f2bf(O[nb][r] * rv[r]);
    }
  }
#undef STAGE
#undef WAITSTAGE
}

// ---------- host ----------
extern "C" void kernel_launch(void* const* d_in, const int* in_sizes, int n_in,
                              void* d_out, int out_size, void* d_ws, size_t ws_size,
                              hipStream_t stream) {
  const int*   positions = (const int*)d_in[0];
  const float* hidden    = (const float*)d_in[1];
  const float* w_q_a     = (const float*)d_in[2];
  const float* q_a_norm  = (const float*)d_in[3];
  const float* w_q_b     = (const float*)d_in[4];
  const float* w_kv_a    = (const float*)d_in[5];
  const float* kv_a_norm = (const float*)d_in[6];
  const float* w_kv_b    = (const float*)d_in[7];
  const float* w_o       = (const float*)d_in[8];
  float* out = (float*)d_out;
  char*  ws  = (char*)d_ws;

  // layout (bytes), total 203,948,032 (same as R9)
  u16* hs_bf  = (u16*)(ws + 0);
  u16* attnb  = (u16*)(ws + 0);
  u16* wab_t  = (u16*)(ws + 20971520);
  u16* q_c_n  = (u16*)(ws + 20971520);
  u16* comp   = (u16*)(ws + 27262976);
  u16* wqb_t  = (u16*)(ws + 44564480);
  u16* wkvb_t = (u16*)(ws + 63438848);
  u16* wo_t   = (u16*)(ws + 71827456);
  float* slabs = (float*)(ws + 113770496);
  u16* q_all  = (u16*)(ws + 113770496);
  u16* k_all  = (u16*)(ws + 138936320);
  u16* v_big  = (u16*)(ws + 170393600);
  u16* v_t    = (u16*)(ws + 187170816);

  // 1) all conversions/transposes (separate, high-occupancy)
  prep_w<<<23296, 256, 0, stream>>>(hidden, hs_bf, w_q_a, w_kv_a, wab_t,
                                    w_q_b, wqb_t, w_kv_b, wkvb_t, w_o, wo_t);

  // 2) merged LoRA-A GEMM: 8-phase 256^2, Npad=2304, split-K=3
  gemm_a8<<<216, 512, 0, stream>>>(hs_bf, wab_t, slabs);

  // 3) merged norms (+rope broadcast into k_all)
  norm_all<<<2048, 256, 0, stream>>>(slabs, q_a_norm, kv_a_norm, positions,
                                     q_c_n, comp, k_all);

  // 4) fused q_b + kv_b with layout/rope epilogues
  gemm_fused_b<<<448, 512, 0, stream>>>(q_c_n, wqb_t, comp, wkvb_t, positions,
                                        q_all, k_all, v_big);

  // 5) V transpose
  v_transpose<<<1024, 256, 0, stream>>>(v_big, v_t);

  // 6) attention
  attn_fwd<<<256, 512, 0, stream>>>(q_all, k_all, v_t, attnb);

  // 7) output projection (8-phase 256^2, 160 blocks)
  gemm_out_k<<<160, 512, 0, stream>>>(attnb, wo_t, out);
}

// Round 12
// 384.986 us; speedup vs baseline: 1.0801x; 1.0297x over previous
//
#include <hip/hip_runtime.h>

typedef unsigned short u16;
typedef unsigned int   u32;
typedef __bf16 bf16x8 __attribute__((ext_vector_type(8)));
typedef float  f32x4  __attribute__((ext_vector_type(4)));
typedef u16    u16x4  __attribute__((ext_vector_type(4)));
typedef u16    u16x8  __attribute__((ext_vector_type(8)));

// ---------- helpers ----------
__device__ __forceinline__ u16 f2bf(float f) {
  u32 u = __float_as_uint(f);
  u32 r = u + 0x7fffu + ((u >> 16) & 1u);   // RTNE
  return (u16)(r >> 16);
}

__device__ __forceinline__ void gl16(const void* g, void* l) {
  __builtin_amdgcn_global_load_lds((__attribute__((address_space(1))) void*)(g),
                                   (__attribute__((address_space(3))) void*)(l),
                                   16, 0, 0);
}

#define WAITVM4  asm volatile("s_waitcnt vmcnt(4)" ::: "memory")
#define WAITVM0  asm volatile("s_waitcnt vmcnt(0)" ::: "memory")
#define WAITLG0  asm volatile("s_waitcnt lgkmcnt(0)" ::: "memory")
#define BAR()    asm volatile("s_barrier" ::: "memory")
#define SCHEDB() __builtin_amdgcn_sched_barrier(0)

// ---------- prep_w: cvt(hidden) + ALL weight transposes + pad zero ----------
__device__ __forceinline__ void tr_tile(const float* __restrict__ W, u16* __restrict__ Wt,
                                        int K, int N, int NT, int idx, float (*tile)[65]) {
  const int tid = threadIdx.x;
  const int nt = idx % NT, kt = idx / NT;
  const int n0 = nt * 64, k0 = kt * 32;
  {
    const int r = tid >> 3, c8 = (tid & 7) << 3;
    const float* src = W + (size_t)(k0 + r) * N + n0 + c8;
    float4 a = *(const float4*)src;
    float4 b = *(const float4*)(src + 4);
    tile[r][c8 + 0] = a.x; tile[r][c8 + 1] = a.y; tile[r][c8 + 2] = a.z; tile[r][c8 + 3] = a.w;
    tile[r][c8 + 4] = b.x; tile[r][c8 + 5] = b.y; tile[r][c8 + 6] = b.z; tile[r][c8 + 7] = b.w;
  }
  __syncthreads();
  const int n = tid >> 2, kg = (tid & 3) << 3;
  u16x8 o;
  #pragma unroll
  for (int j = 0; j < 8; ++j) o[j] = f2bf(tile[kg + j][n]);
  *(u16x8*)(Wt + (size_t)(n0 + n) * K + k0 + kg) = o;
}

// wab_t: merged [2304][5120]: rows 0..1535 = wqa^T, 1536..2111 = wkva^T, 2112..2303 = 0
__global__ __launch_bounds__(256) void prep_w(const float* __restrict__ hidden, u16* __restrict__ hs_bf,
                                              const float* __restrict__ wqa,
                                              const float* __restrict__ wkva, u16* __restrict__ wab_t,
                                              const float* __restrict__ wqb,  u16* __restrict__ wqb_t,
                                              const float* __restrict__ wkvb, u16* __restrict__ wkvb_t,
                                              const float* __restrict__ wo,   u16* __restrict__ wo_t) {
  __shared__ float tile[32][65];
  const int b = blockIdx.x, tid = threadIdx.x;
  if (b < 640) {                       // cvt: hidden [2048][5120] f32 -> bf16
    const float4* xin = (const float4*)hidden;
    #pragma unroll
    for (int j = 0; j < 8; ++j) {
      int u = b * 2048 + j * 256 + tid;
      float4 a = xin[u * 2], c = xin[u * 2 + 1];
      u16x8 o;
      o[0] = f2bf(a.x); o[1] = f2bf(a.y); o[2] = f2bf(a.z); o[3] = f2bf(a.w);
      o[4] = f2bf(c.x); o[5] = f2bf(c.y); o[6] = f2bf(c.z); o[7] = f2bf(c.w);
      *(u16x8*)(hs_bf + (size_t)u * 8) = o;
    }
  } else if (b < 4480) {               // w_q_a [5120][1536] -> wab_t rows 0..1535
    tr_tile(wqa, wab_t, 5120, 1536, 24, b - 640, tile);
  } else if (b < 5920) {               // w_kv_a [5120][576] -> wab_t rows 1536..2111
    tr_tile(wkva, wab_t + (size_t)1536 * 5120, 5120, 576, 9, b - 4480, tile);
  } else if (b < 10528) {              // w_q_b [1536][6144]
    tr_tile(wqb, wqb_t, 1536, 6144, 96, b - 5920, tile);
  } else if (b < 12576) {              // w_kv_b [512][8192]
    tr_tile(wkvb, wkvb_t, 512, 8192, 128, b - 10528, tile);
  } else if (b < 22816) {              // w_o [4096][5120]
    tr_tile(wo, wo_t, 4096, 5120, 80, b - 12576, tile);
  } else {                             // zero wab_t rows 2112..2303 (480 blocks)
    size_t off = (size_t)(b - 22816) * 4096 + tid * 16;
    u16x8 z = {};
    *(u16x8*)((char*)wab_t + (size_t)2112 * 5120 * 2 + off) = z;
  }
}

// ---------- shared 8-phase 256x256 GEMM body ----------
// EPI=0: f32 C   EPI=1: q->rope->q_all   EPI=2: kv->k_all + v_t (fused transpose)
template<int EPI>
__device__ __forceinline__ void gemm8_body(char* lds,
                                           const u16* __restrict__ A,
                                           const u16* __restrict__ Bt,
                                           int N, int K, int wg, int nwg, int nbx,
                                           int nkt, int kt0,
                                           const int* __restrict__ pos,
                                           u16* __restrict__ q_all,
                                           u16* __restrict__ k_all,
                                           u16* __restrict__ v_t,
                                           float* __restrict__ Cf) {
  const int tid = threadIdx.x;
  const int lane = tid & 63, wid = tid >> 6;
  const int wr = wid >> 2, wc = wid & 3;
  const int lr = lane & 15, lg = lane >> 4;

  const int swz = ((nwg & 7) == 0) ? ((wg & 7) * (nwg >> 3) + (wg >> 3)) : wg;
  const int bx = swz % nbx, by = swz / nbx;
  const int m0 = by << 8, n0 = bx << 8;

  const size_t rs = (size_t)K << 1;
  const char* Ab = (const char*)A;
  const char* Bb = (const char*)Bt;

  const int sofs = tid << 4;
  const int srow = sofs >> 7;
  const int scol = ((((sofs >> 4) & 7) ^ (srow & 7)) << 4);

  const int axor = lr & 7;
  const int sx0 = (lg ^ axor) << 4;
  const int sx1 = ((4 | lg) ^ axor) << 4;
  const int bcolbase = (wc & 1) << 13;

  f32x4 acc[8][4] = {};

#define ASL(p,h) ((((p) << 1) | (h)) << 14)
#define BSL(p,h) (65536 + ((((p) << 1) | (h)) << 14))
#define STAGE_HALF(gb, grow0, kt, slot)                                              \
  { const char* _s = (gb) + (size_t)(grow0) * rs + ((size_t)((kt) + kt0) << 7) + scol; \
    gl16(_s, lds + (slot) + sofs);                                                   \
    gl16(_s + (rs << 6), lds + (slot) + sofs + 8192); }

  STAGE_HALF(Ab, m0 + srow,       0, ASL(0,0));
  STAGE_HALF(Ab, m0 + 128 + srow, 0, ASL(0,1));
  STAGE_HALF(Bb, n0 + srow,       0, BSL(0,0));
  STAGE_HALF(Bb, n0 + 128 + srow, 0, BSL(0,1));
  if (nkt > 1) {
    STAGE_HALF(Bb, n0 + srow,       1, BSL(1,0));
    STAGE_HALF(Bb, n0 + 128 + srow, 1, BSL(1,1));
    WAITVM4;
  } else {
    WAITVM0;
  }
  BAR();

  for (int b = 0; b < nkt; ++b) {
    const int p = b & 1;
    const int abase = ASL(p, wr);
    const int bbase = BSL(p, (wc >> 1)) + bcolbase;
    bf16x8 aR[4][2], bR[4][2];

    #pragma unroll
    for (int m = 0; m < 4; ++m) {
      aR[m][0] = *(const bf16x8*)(lds + abase + (m * 16 + lr) * 128 + sx0);
      aR[m][1] = *(const bf16x8*)(lds + abase + (m * 16 + lr) * 128 + sx1);
    }
    #pragma unroll
    for (int n = 0; n < 2; ++n) {
      bR[n][0] = *(const bf16x8*)(lds + bbase + (n * 16 + lr) * 128 + sx0);
      bR[n][1] = *(const bf16x8*)(lds + bbase + (n * 16 + lr) * 128 + sx1);
    }
    if (b + 1 < nkt) { STAGE_HALF(Ab, m0 + srow, b + 1, ASL((b + 1) & 1, 0)); }
    BAR(); WAITLG0; SCHEDB();
    __builtin_amdgcn_s_setprio(1);
    #pragma unroll
    for (int kf = 0; kf < 2; ++kf)
      #pragma unroll
      for (int m = 0; m < 4; ++m)
        #pragma unroll
        for (int n = 0; n < 2; ++n)
          acc[m][n] = __builtin_amdgcn_mfma_f32_16x16x32_bf16(aR[m][kf], bR[n][kf], acc[m][n], 0, 0, 0);
    __builtin_amdgcn_s_setprio(0); SCHEDB();
    BAR();

    #pragma unroll
    for (int n = 2; n < 4; ++n) {
      bR[n][0] = *(const bf16x8*)(lds + bbase + (n * 16 + lr) * 128 + sx0);
      bR[n][1] = *(const bf16x8*)(lds + bbase + (n * 16 + lr) * 128 + sx1);
    }
    if (b + 1 < nkt) { STAGE_HALF(Ab, m0 + 128 + srow, b + 1, ASL((b + 1) & 1, 1)); }
    BAR(); WAITLG0; SCHEDB();
    __builtin_amdgcn_s_setprio(1);
    #pragma unroll
    for (int kf = 0; kf < 2; ++kf)
      #pragma unroll
      for (int m = 0; m < 4; ++m)
        #pragma unroll
        for (int n = 2; n < 4; ++n)
          acc[m][n] = __builtin_amdgcn_mfma_f32_16x16x32_bf16(aR[m][kf], bR[n][kf], acc[m][n], 0, 0, 0);
    __builtin_amdgcn_s_setprio(0); SCHEDB();
    BAR();

    #pragma unroll
    for (int m = 0; m < 4; ++m) {
      aR[m][0] = *(const bf16x8*)(lds + abase + ((m + 4) * 16 + lr) * 128 + sx0);
      aR[m][1] = *(const bf16x8*)(lds + abase + ((m + 4) * 16 + lr) * 128 + sx1);
    }
    if (b + 2 < nkt) { STAGE_HALF(Bb, n0 + srow, b + 2, BSL(p, 0)); }
    BAR(); WAITLG0; SCHEDB();
    __builtin_amdgcn_s_setprio(1);
    #pragma unroll
    for (int kf = 0; kf < 2; ++kf)
      #pragma unroll
      for (int m = 0; m < 4; ++m)
        #pragma unroll
        for (int n = 0; n < 2; ++n)
          acc[m + 4][n] = __builtin_amdgcn_mfma_f32_16x16x32_bf16(aR[m][kf], bR[n][kf], acc[m + 4][n], 0, 0, 0);
    __builtin_amdgcn_s_setprio(0); SCHEDB();
    BAR();

    if (b + 2 < nkt) { STAGE_HALF(Bb, n0 + 128 + srow, b + 2, BSL(p, 1)); }
    BAR(); SCHEDB();
    __builtin_amdgcn_s_setprio(1);
    #pragma unroll
    for (int kf = 0; kf < 2; ++kf)
      #pragma unroll
      for (int m = 0; m < 4; ++m)
        #pragma unroll
        for (int n = 2; n < 4; ++n)
          acc[m + 4][n] = __builtin_amdgcn_mfma_f32_16x16x32_bf16(aR[m][kf], bR[n][kf], acc[m + 4][n], 0, 0, 0);
    __builtin_amdgcn_s_setprio(0); SCHEDB();
    if (b + 2 < nkt) { WAITVM4; } else { WAITVM0; }
    BAR();
  }

  // ---- epilogue ----
  if (EPI == 0) {
    #pragma unroll
    for (int m = 0; m < 8; ++m) {
      const int row0 = m0 + wr * 128 + m * 16 + lg * 4;
      #pragma unroll
      for (int n = 0; n < 4; ++n) {
        const int col = n0 + wc * 64 + n * 16 + lr;
        #pragma unroll
        for (int r = 0; r < 4; ++r)
          Cf[(size_t)(row0 + r) * N + col] = acc[m][n][r];
      }
    }
  } else if (EPI == 1) {
    int hh[4], dd[4]; float inv[4]; bool rope[4];
    #pragma unroll
    for (int n = 0; n < 4; ++n) {
      int col = n0 + wc * 64 + n * 16 + lr;
      hh[n] = col / 192;
      dd[n] = col - hh[n] * 192;
      rope[n] = (dd[n] >= 128);
      int i = (dd[n] - 128) >> 1;
      inv[n] = rope[n] ? exp2f(-(float)i * 0.41524101186092f) : 0.f;
    }
    const bool odd = (lr & 1);
    #pragma unroll
    for (int m = 0; m < 8; ++m) {
      const int row0 = m0 + wr * 128 + m * 16 + lg * 4;
      #pragma unroll
      for (int r = 0; r < 4; ++r) {
        const int row = row0 + r;
        const float pv = (float)pos[row];
        #pragma unroll
        for (int n = 0; n < 4; ++n) {
          float v = acc[m][n][r];
          float o = __shfl_xor(v, 1, 64);
          if (rope[n]) {
            float s, c;
            __sincosf(pv * inv[n], &s, &c);
            v = odd ? (o * s + v * c) : (v * c - o * s);
          }
          q_all[((size_t)hh[n] * 2048 + row) * 192 + dd[n]] = f2bf(v);
        }
      }
    }
  } else {
    // kv: col -> (h = col>>8, dd). dd<128 -> k_all nope (scalar, strided).
    // dd>=128 -> v_t[h][dd-128][row] with 4 consecutive rows = packed u16x4.
    #pragma unroll
    for (int n = 0; n < 4; ++n) {
      const int col = n0 + wc * 64 + n * 16 + lr;
      const int h = col >> 8, dd = col & 255;          // wave-uniform side of 128
      if (dd < 128) {
        #pragma unroll
        for (int m = 0; m < 8; ++m) {
          const int row0 = m0 + wr * 128 + m * 16 + lg * 4;
          #pragma unroll
          for (int r = 0; r < 4; ++r)
            k_all[((size_t)h * 2048 + row0 + r) * 200 + dd] = f2bf(acc[m][n][r]);
        }
      } else {
        u16* vb = v_t + ((size_t)h * 128 + (dd - 128)) * 2048;
        #pragma unroll
        for (int m = 0; m < 8; ++m) {
          const int row0 = m0 + wr * 128 + m * 16 + lg * 4;
          u16x4 o;
          o[0] = f2bf(acc[m][n][0]); o[1] = f2bf(acc[m][n][1]);
          o[2] = f2bf(acc[m][n][2]); o[3] = f2bf(acc[m][n][3]);
          *(u16x4*)(vb + row0) = o;
        }
      }
    }
  }
#undef ASL
#undef BSL
#undef STAGE_HALF
}

// ---------- LoRA-A GEMM: 8-phase 256^2, Npad=2304, split-K=3 into slabs ----------
#define SLAB2 ((size_t)2048 * 2304)
__global__ __launch_bounds__(512, 2) void gemm_a8(const u16* __restrict__ A,
                                                  const u16* __restrict__ Bt,
                                                  float* __restrict__ C) {
  __shared__ char lds[131072];
  const int z = blockIdx.x / 72;                 // 0..2
  const int wg = blockIdx.x - z * 72;
  const int nkt = (z == 2) ? 26 : 27;            // 27+27+26 = 80 k-tiles (K=5120)
  gemm8_body<0>(lds, A, Bt, 2304, 5120, wg, 72, 9, nkt, z * 27,
                nullptr, nullptr, nullptr, nullptr, C + (size_t)z * SLAB2);
}

// ---------- fused q_b + kv_b launch with fused epilogues (kv writes v_t directly) ----------
__global__ __launch_bounds__(512, 2) void gemm_fused_b(const u16* __restrict__ A1,
                                                       const u16* __restrict__ B1,
                                                       const u16* __restrict__ A2,
                                                       const u16* __restrict__ B2,
                                                       const int* __restrict__ pos,
                                                       u16* __restrict__ q_all,
                                                       u16* __restrict__ k_all,
                                                       u16* __restrict__ v_t) {
  __shared__ char lds[131072];
  if (blockIdx.x < 192)
    gemm8_body<1>(lds, A1, B1, 6144, 1536, blockIdx.x, 192, 24, 24, 0, pos, q_all, nullptr, nullptr, nullptr);
  else
    gemm8_body<2>(lds, A2, B2, 8192, 512, blockIdx.x - 192, 256, 32, 8, 0, pos, nullptr, k_all, v_t, nullptr);
}

// ---------- out-projection (8-phase 256^2, f32 C) ----------
__global__ __launch_bounds__(512, 2) void gemm_out_k(const u16* __restrict__ A,
                                                     const u16* __restrict__ Bt,
                                                     float* __restrict__ C) {
  __shared__ char lds[131072];
  gemm8_body<0>(lds, A, Bt, 5120, 4096, blockIdx.x, 160, 20, 64, 0,
                nullptr, nullptr, nullptr, nullptr, C);
}

// ---------- merged norms: RMSNorm(q) + RMSNorm(kv) + RoPE(k) + k_all rope broadcast ----------
__global__ __launch_bounds__(256) void norm_all(const float* __restrict__ slabs,
                                                const float* __restrict__ wq,
                                                const float* __restrict__ wkv,
                                                const int* __restrict__ pos,
                                                u16* __restrict__ q_c_n,
                                                u16* __restrict__ comp,
                                                u16* __restrict__ k_all) {
  const int row = blockIdx.x, tid = threadIdx.x;
  const float* xr = slabs + (size_t)row * 2304;
  __shared__ float sm[4];
  __shared__ u16 krv[64];

  // ---- q part (cols 0..1535) ----
  float v[6]; float ss = 0.f;
  #pragma unroll
  for (int i = 0; i < 6; ++i) {
    size_t o = tid + i * 256;
    v[i] = xr[o] + xr[o + SLAB2] + xr[o + 2 * SLAB2];
    ss += v[i] * v[i];
  }
  #pragma unroll
  for (int o = 32; o > 0; o >>= 1) ss += __shfl_down(ss, o, 64);
  if ((tid & 63) == 0) sm[tid >> 6] = ss;
  __syncthreads();
  float rsq = rsqrtf((sm[0] + sm[1] + sm[2] + sm[3]) * (1.f / 1536.f) + 1e-6f);
  #pragma unroll
  for (int i = 0; i < 6; ++i)
    q_c_n[(size_t)row * 1536 + tid + i * 256] = f2bf(v[i] * rsq * wq[tid + i * 256]);

  // ---- kv part (cols 1536..2047 norm; 2048..2111 rope) ----
  const float* xk = xr + 1536;
  float v0 = xk[tid] + xk[tid + SLAB2] + xk[tid + 2 * SLAB2];
  size_t o1 = tid + 256;
  float v1 = xk[o1] + xk[o1 + SLAB2] + xk[o1 + 2 * SLAB2];
  float ss2 = v0 * v0 + v1 * v1;
  #pragma unroll
  for (int o = 32; o > 0; o >>= 1) ss2 += __shfl_down(ss2, o, 64);
  __syncthreads();                    // all sm reads from q-phase done
  if ((tid & 63) == 0) sm[tid >> 6] = ss2;
  if (tid < 32) {
    float p = (float)pos[row];
    float inv = powf(10000.0f, -(float)(2 * tid) * (1.0f / 64.0f));
    float ang = p * inv;
    float c = cosf(ang), s = sinf(ang);
    size_t e1 = 512 + 2 * tid, e2 = e1 + 1;
    float x1 = xk[e1] + xk[e1 + SLAB2] + xk[e1 + 2 * SLAB2];
    float x2 = xk[e2] + xk[e2 + SLAB2] + xk[e2 + 2 * SLAB2];
    krv[2 * tid]     = f2bf(x1 * c - x2 * s);
    krv[2 * tid + 1] = f2bf(x1 * s + x2 * c);
  }
  __syncthreads();
  float rsk = rsqrtf((sm[0] + sm[1] + sm[2] + sm[3]) * (1.f / 512.f) + 1e-6f);
  comp[(size_t)row * 512 + tid]       = f2bf(v0 * rsk * wkv[tid]);
  comp[(size_t)row * 512 + tid + 256] = f2bf(v1 * rsk * wkv[tid + 256]);

  const int h = tid >> 3, j8 = (tid & 7) << 3;
  *(u16x8*)&k_all[((size_t)h * 2048 + row) * 200 + 128 + j8] = *(const u16x8*)&krv[j8];
}

// ---------- flash attention: 8 waves, 128q x 64s tiles, dbuf, swapped-QK, setprio ----------
#define SCL2 0.10412706f
#define THR2 11.5f
__global__ __launch_bounds__(512, 2) void attn_fwd(const u16* __restrict__ q_all,
                                                   const u16* __restrict__ k_all,
                                                   const u16* __restrict__ v_t,
                                                   u16* __restrict__ attnb) {
  __shared__ __align__(16) char lds[106496];
  const int tid = threadIdx.x;
  const int lane = tid & 63, wid = tid >> 6;
  const int lr = lane & 15, lg = lane >> 4;
  const int h = blockIdx.x & 31, bq = blockIdx.x >> 5;

  const char* kh = (const char*)(k_all + (size_t)h * 2048 * 200);
  const char* vh = (const char*)(v_t + (size_t)h * 128 * 2048);
  char* Pw = lds + 88064 + wid * 2304;

  const int nCalls = (wid < 3) ? 6 : 5;
  const char* gp[6]; int cofs[6]; int isK[6];
  #pragma unroll
  for (int ii = 0; ii < 6; ++ii) {
    int i = wid + (ii << 3);
    if (i < 43) {
      int c = (i << 6) + lane;
      cofs[ii] = c << 4;
      if (c < 1600) { gp[ii] = kh + ((size_t)c << 4); isK[ii] = 1; }
      else {
        int cv = c - 1600;
        int row = cv / 9, sub = cv - row * 9;
        gp[ii] = vh + ((size_t)row << 12) + ((sub < 8) ? (sub << 4) : 0);
        isK[ii] = 0;
      }
    } else { gp[ii] = kh; cofs[ii] = 0; isK[ii] = 1; }
  }

#define STAGE(s0_, bOff_)                                                       \
  { int _sk = (s0_) * 400, _sv = (s0_) * 2;                                     \
    _Pragma("unroll")                                                           \
    for (int ii = 0; ii < 6; ++ii)                                              \
      if (ii < nCalls)                                                          \
        gl16(gp[ii] + (isK[ii] ? _sk : _sv), lds + (bOff_) + cofs[ii]); }

#define WAITSTAGE                                                               \
  { if (wid < 3) { asm volatile("s_waitcnt vmcnt(6)" ::: "memory"); }           \
    else        { asm volatile("s_waitcnt vmcnt(5)" ::: "memory"); } }

  const int kRd = lr * 400 + lg * 16;
  const int vRd = lr * 144 + lg * 16;
  const int pRd = lr * 144 + lg * 16;
  const int pWr = lr * 144 + lg * 8;

  #pragma unroll
  for (int half = 0; half < 2; ++half) {
    const int qt = half ? (15 - bq) : bq;
    const int qb0 = qt << 7;
    const int nt = 2 * qt + 2;
    const int qlane = qb0 + wid * 16 + lr;
    const int qwmin = qb0 + wid * 16;

    bf16x8 qf[6];
    const u16* qptr = q_all + ((size_t)h * 2048 + qlane) * 192 + lg * 8;
    #pragma unroll
    for (int kf = 0; kf < 6; ++kf) qf[kf] = *(const bf16x8*)(qptr + kf * 32);

    f32x4 O[8] = {};
    float m = -1e30f, l = 0.f;

    STAGE(0, 0);
    for (int st = 0; st < nt; ++st) {
      const int s0 = st << 6;
      const int bOff = (st & 1) * 44032;
      if (st + 1 < nt) {
        STAGE((st + 1) << 6, ((st + 1) & 1) * 44032);
        WAITSTAGE;
      } else {
        WAITVM0;
      }
      BAR();

      const bool active = (s0 <= qwmin + 15);
      if (active) {
        const char* Kb = lds + bOff;
        const char* Vb = lds + bOff + 25600;

        f32x4 S[4];
        __builtin_amdgcn_s_setprio(1);
        #pragma unroll
        for (int sb = 0; sb < 4; ++sb) {
          f32x4 a = {};
          #pragma unroll
          for (int kf = 0; kf < 6; ++kf) {
            bf16x8 kfr = *(const bf16x8*)(Kb + kRd + sb * 6400 + kf * 64);
            a = __builtin_amdgcn_mfma_f32_16x16x32_bf16(kfr, qf[kf], a, 0, 0, 0);
          }
          S[sb] = a;
        }
        __builtin_amdgcn_s_setprio(0);

        if (s0 + 63 > qwmin) {
          const int kb0 = s0 + lg * 4;
          #pragma unroll
          for (int sb = 0; sb < 4; ++sb)
            #pragma unroll
            for (int r = 0; r < 4; ++r) {
              int k = kb0 + sb * 16 + r;
              S[sb][r] = (k > qlane) ? -1e30f : S[sb][r] * SCL2;
            }
        } else {
          #pragma unroll
          for (int sb = 0; sb < 4; ++sb)
            #pragma unroll
            for (int r = 0; r < 4; ++r) S[sb][r] *= SCL2;
        }

        float mx = S[0][0];
        #pragma unroll
        for (int sb = 0; sb < 4; ++sb)
          #pragma unroll
          for (int r = 0; r < 4; ++r) mx = fmaxf(mx, S[sb][r]);
        mx = fmaxf(mx, __shfl_xor(mx, 16, 64));
        mx = fmaxf(mx, __shfl_xor(mx, 32, 64));

        const bool skip = __all(mx <= m + THR2);
        float alpha = 1.f;
        if (!skip) { float mn = fmaxf(m, mx); alpha = exp2f(m - mn); m = mn; }

        float ps = 0.f;
        #pragma unroll
        for (int sb = 0; sb < 4; ++sb)
          #pragma unroll
          for (int r = 0; r < 4; ++r) {
            float pv = exp2f(S[sb][r] - m);
            S[sb][r] = pv;
            ps += pv;
          }
        ps += __shfl_xor(ps, 16, 64);
        ps += __shfl_xor(ps, 32, 64);
        l = l * alpha + ps;

        if (!skip) {
          float aO[4];
          #pragma unroll
          for (int r = 0; r < 4; ++r) aO[r] = __shfl(alpha, lg * 4 + r, 64);
          #pragma unroll
          for (int nb = 0; nb < 8; ++nb)
            #pragma unroll
            for (int r = 0; r < 4; ++r) O[nb][r] *= aO[r];
        }

        #pragma unroll
        for (int sb = 0; sb < 4; ++sb) {
          u32 p01, p23;
          asm("v_cvt_pk_bf16_f32 %0, %1, %2" : "=v"(p01) : "v"(S[sb][0]), "v"(S[sb][1]));
          asm("v_cvt_pk_bf16_f32 %0, %1, %2" : "=v"(p23) : "v"(S[sb][2]), "v"(S[sb][3]));
          *(uint2*)(Pw + pWr + sb * 32) = make_uint2(p01, p23);
        }

        __builtin_amdgcn_s_setprio(1);
        #pragma unroll
        for (int k2 = 0; k2 < 2; ++k2) {
          bf16x8 pa = *(const bf16x8*)(Pw + pRd + k2 * 64);
          #pragma unroll
          for (int nb = 0; nb < 8; ++nb) {
            bf16x8 vf = *(const bf16x8*)(Vb + vRd + nb * 2304 + k2 * 64);
            O[nb] = __builtin_amdgcn_mfma_f32_16x16x32_bf16(pa, vf, O[nb], 0, 0, 0);
          }
        }
        __builtin_amdgcn_s_setprio(0);
      }
      BAR();
    }

    float rv[4];
    #pragma unroll
    for (int r = 0; r < 4; ++r) rv[r] = 1.f / __shfl(l, lg * 4 + r, 64);
    #pragma unroll
    for (int nb = 0; nb < 8; ++nb) {
      const int col = h * 128 + nb * 16 + lr;
      #pragma unroll
      for (int r = 0; r < 4; ++r)
        attnb[(size_t)(qb0 + wid * 16 + lg * 4 + r) * 4096 + col] = f2bf(O[nb][r] * rv[r]);
    }
  }
#undef STAGE
#undef WAITSTAGE
}

// ---------- host ----------
extern "C" void kernel_launch(void* const* d_in, const int* in_sizes, int n_in,
                              void* d_out, int out_size, void* d_ws, size_t ws_size,
                              hipStream_t stream) {
  const int*   positions = (const int*)d_in[0];
  const float* hidden    = (const float*)d_in[1];
  const float* w_q_a     = (const float*)d_in[2];
  const float* q_a_norm  = (const float*)d_in[3];
  const float* w_q_b     = (const float*)d_in[4];
  const float* w_kv_a    = (const float*)d_in[5];
  const float* kv_a_norm = (const float*)d_in[6];
  const float* w_kv_b    = (const float*)d_in[7];
  const float* w_o       = (const float*)d_in[8];
  float* out = (float*)d_out;
  char*  ws  = (char*)d_ws;

  // layout (bytes), total 203,948,032 (v_big slot now unused)
  u16* hs_bf  = (u16*)(ws + 0);
  u16* attnb  = (u16*)(ws + 0);
  u16* wab_t  = (u16*)(ws + 20971520);
  u16* q_c_n  = (u16*)(ws + 20971520);
  u16* comp   = (u16*)(ws + 27262976);
  u16* wqb_t  = (u16*)(ws + 44564480);
  u16* wkvb_t = (u16*)(ws + 63438848);
  u16* wo_t   = (u16*)(ws + 71827456);
  float* slabs = (float*)(ws + 113770496);
  u16* q_all  = (u16*)(ws + 113770496);
  u16* k_all  = (u16*)(ws + 138936320);
  u16* v_t    = (u16*)(ws + 187170816);

  // 1) all conversions/transposes (separate, high-occupancy)
  prep_w<<<23296, 256, 0, stream>>>(hidden, hs_bf, w_q_a, w_kv_a, wab_t,
                                    w_q_b, wqb_t, w_kv_b, wkvb_t, w_o, wo_t);

  // 2) merged LoRA-A GEMM: 8-phase 256^2, Npad=2304, split-K=3
  gemm_a8<<<216, 512, 0, stream>>>(hs_bf, wab_t, slabs);

  // 3) merged norms (+rope broadcast into k_all)
  norm_all<<<2048, 256, 0, stream>>>(slabs, q_a_norm, kv_a_norm, positions,
                                     q_c_n, comp, k_all);

  // 4) fused q_b + kv_b with layout/rope epilogues (kv writes k_all + v_t directly)
  gemm_fused_b<<<448, 512, 0, stream>>>(q_c_n, wqb_t, comp, wkvb_t, positions,
                                        q_all, k_all, v_t);

  // 5) attention
  attn_fwd<<<256, 512, 0, stream>>>(q_all, k_all, v_t, attnb);

  // 6) output projection (8-phase 256^2, 160 blocks)
  gemm_out_k<<<160, 512, 0, stream>>>(attnb, wo_t, out);
}

// Round 13
// 378.847 us; speedup vs baseline: 1.0976x; 1.0162x over previous
//
#include <hip/hip_runtime.h>

typedef unsigned short u16;
typedef unsigned int   u32;
typedef __bf16 bf16x8 __attribute__((ext_vector_type(8)));
typedef float  f32x4  __attribute__((ext_vector_type(4)));
typedef u16    u16x4  __attribute__((ext_vector_type(4)));
typedef u16    u16x8  __attribute__((ext_vector_type(8)));

// ---------- helpers ----------
__device__ __forceinline__ u16 f2bf(float f) {
  u32 u = __float_as_uint(f);
  u32 r = u + 0x7fffu + ((u >> 16) & 1u);   // RTNE
  return (u16)(r >> 16);
}
__device__ __forceinline__ float b2f(u16 v) {
  return __uint_as_float((u32)v << 16);
}

__device__ __forceinline__ void gl16(const void* g, void* l) {
  __builtin_amdgcn_global_load_lds((__attribute__((address_space(1))) void*)(g),
                                   (__attribute__((address_space(3))) void*)(l),
                                   16, 0, 0);
}

#define WAITVM4  asm volatile("s_waitcnt vmcnt(4)" ::: "memory")
#define WAITVM0  asm volatile("s_waitcnt vmcnt(0)" ::: "memory")
#define WAITLG0  asm volatile("s_waitcnt lgkmcnt(0)" ::: "memory")
#define BAR()    asm volatile("s_barrier" ::: "memory")
#define SCHEDB() __builtin_amdgcn_sched_barrier(0)

// ---------- prep_w: cvt(hidden) + ALL weight transposes + pad zero ----------
__device__ __forceinline__ void tr_tile(const float* __restrict__ W, u16* __restrict__ Wt,
                                        int K, int N, int NT, int idx, float (*tile)[65]) {
  const int tid = threadIdx.x;
  const int nt = idx % NT, kt = idx / NT;
  const int n0 = nt * 64, k0 = kt * 32;
  {
    const int r = tid >> 3, c8 = (tid & 7) << 3;
    const float* src = W + (size_t)(k0 + r) * N + n0 + c8;
    float4 a = *(const float4*)src;
    float4 b = *(const float4*)(src + 4);
    tile[r][c8 + 0] = a.x; tile[r][c8 + 1] = a.y; tile[r][c8 + 2] = a.z; tile[r][c8 + 3] = a.w;
    tile[r][c8 + 4] = b.x; tile[r][c8 + 5] = b.y; tile[r][c8 + 6] = b.z; tile[r][c8 + 7] = b.w;
  }
  __syncthreads();
  const int n = tid >> 2, kg = (tid & 3) << 3;
  u16x8 o;
  #pragma unroll
  for (int j = 0; j < 8; ++j) o[j] = f2bf(tile[kg + j][n]);
  *(u16x8*)(Wt + (size_t)(n0 + n) * K + k0 + kg) = o;
}

// wab_t: merged [2304][5120]: rows 0..1535 = wqa^T, 1536..2111 = wkva^T, 2112..2303 = 0
__global__ __launch_bounds__(256) void prep_w(const float* __restrict__ hidden, u16* __restrict__ hs_bf,
                                              const float* __restrict__ wqa,
                                              const float* __restrict__ wkva, u16* __restrict__ wab_t,
                                              const float* __restrict__ wqb,  u16* __restrict__ wqb_t,
                                              const float* __restrict__ wkvb, u16* __restrict__ wkvb_t,
                                              const float* __restrict__ wo,   u16* __restrict__ wo_t) {
  __shared__ float tile[32][65];
  const int b = blockIdx.x, tid = threadIdx.x;
  if (b < 640) {                       // cvt: hidden [2048][5120] f32 -> bf16
    const float4* xin = (const float4*)hidden;
    #pragma unroll
    for (int j = 0; j < 8; ++j) {
      int u = b * 2048 + j * 256 + tid;
      float4 a = xin[u * 2], c = xin[u * 2 + 1];
      u16x8 o;
      o[0] = f2bf(a.x); o[1] = f2bf(a.y); o[2] = f2bf(a.z); o[3] = f2bf(a.w);
      o[4] = f2bf(c.x); o[5] = f2bf(c.y); o[6] = f2bf(c.z); o[7] = f2bf(c.w);
      *(u16x8*)(hs_bf + (size_t)u * 8) = o;
    }
  } else if (b < 4480) {               // w_q_a [5120][1536] -> wab_t rows 0..1535
    tr_tile(wqa, wab_t, 5120, 1536, 24, b - 640, tile);
  } else if (b < 5920) {               // w_kv_a [5120][576] -> wab_t rows 1536..2111
    tr_tile(wkva, wab_t + (size_t)1536 * 5120, 5120, 576, 9, b - 4480, tile);
  } else if (b < 10528) {              // w_q_b [1536][6144]
    tr_tile(wqb, wqb_t, 1536, 6144, 96, b - 5920, tile);
  } else if (b < 12576) {              // w_kv_b [512][8192]
    tr_tile(wkvb, wkvb_t, 512, 8192, 128, b - 10528, tile);
  } else if (b < 22816) {              // w_o [4096][5120]
    tr_tile(wo, wo_t, 4096, 5120, 80, b - 12576, tile);
  } else {                             // zero wab_t rows 2112..2303 (480 blocks)
    size_t off = (size_t)(b - 22816) * 4096 + tid * 16;
    u16x8 z = {};
    *(u16x8*)((char*)wab_t + (size_t)2112 * 5120 * 2 + off) = z;
  }
}

// ---------- shared 8-phase 256x256 GEMM body ----------
// EPI=0: f32 C (nontemporal)  EPI=1: q->rope->q_all  EPI=2: kv->k_all + v_t  EPI=3: bf16 C
template<int EPI>
__device__ __forceinline__ void gemm8_body(char* lds,
                                           const u16* __restrict__ A,
                                           const u16* __restrict__ Bt,
                                           int N, int K, int wg, int nwg, int nbx,
                                           int nkt, int kt0,
                                           const int* __restrict__ pos,
                                           u16* __restrict__ q_all,
                                           u16* __restrict__ k_all,
                                           u16* __restrict__ v_t,
                                           float* __restrict__ Cf) {
  const int tid = threadIdx.x;
  const int lane = tid & 63, wid = tid >> 6;
  const int wr = wid >> 2, wc = wid & 3;
  const int lr = lane & 15, lg = lane >> 4;

  const int swz = ((nwg & 7) == 0) ? ((wg & 7) * (nwg >> 3) + (wg >> 3)) : wg;
  const int bx = swz % nbx, by = swz / nbx;
  const int m0 = by << 8, n0 = bx << 8;

  const size_t rs = (size_t)K << 1;
  const char* Ab = (const char*)A;
  const char* Bb = (const char*)Bt;

  const int sofs = tid << 4;
  const int srow = sofs >> 7;
  const int scol = ((((sofs >> 4) & 7) ^ (srow & 7)) << 4);

  const int axor = lr & 7;
  const int sx0 = (lg ^ axor) << 4;
  const int sx1 = ((4 | lg) ^ axor) << 4;
  const int bcolbase = (wc & 1) << 13;

  f32x4 acc[8][4] = {};

#define ASL(p,h) ((((p) << 1) | (h)) << 14)
#define BSL(p,h) (65536 + ((((p) << 1) | (h)) << 14))
#define STAGE_HALF(gb, grow0, kt, slot)                                              \
  { const char* _s = (gb) + (size_t)(grow0) * rs + ((size_t)((kt) + kt0) << 7) + scol; \
    gl16(_s, lds + (slot) + sofs);                                                   \
    gl16(_s + (rs << 6), lds + (slot) + sofs + 8192); }

  STAGE_HALF(Ab, m0 + srow,       0, ASL(0,0));
  STAGE_HALF(Ab, m0 + 128 + srow, 0, ASL(0,1));
  STAGE_HALF(Bb, n0 + srow,       0, BSL(0,0));
  STAGE_HALF(Bb, n0 + 128 + srow, 0, BSL(0,1));
  if (nkt > 1) {
    STAGE_HALF(Bb, n0 + srow,       1, BSL(1,0));
    STAGE_HALF(Bb, n0 + 128 + srow, 1, BSL(1,1));
    WAITVM4;
  } else {
    WAITVM0;
  }
  BAR();

  for (int b = 0; b < nkt; ++b) {
    const int p = b & 1;
    const int abase = ASL(p, wr);
    const int bbase = BSL(p, (wc >> 1)) + bcolbase;
    bf16x8 aR[4][2], bR[4][2];

    #pragma unroll
    for (int m = 0; m < 4; ++m) {
      aR[m][0] = *(const bf16x8*)(lds + abase + (m * 16 + lr) * 128 + sx0);
      aR[m][1] = *(const bf16x8*)(lds + abase + (m * 16 + lr) * 128 + sx1);
    }
    #pragma unroll
    for (int n = 0; n < 2; ++n) {
      bR[n][0] = *(const bf16x8*)(lds + bbase + (n * 16 + lr) * 128 + sx0);
      bR[n][1] = *(const bf16x8*)(lds + bbase + (n * 16 + lr) * 128 + sx1);
    }
    if (b + 1 < nkt) { STAGE_HALF(Ab, m0 + srow, b + 1, ASL((b + 1) & 1, 0)); }
    BAR(); WAITLG0; SCHEDB();
    __builtin_amdgcn_s_setprio(1);
    #pragma unroll
    for (int kf = 0; kf < 2; ++kf)
      #pragma unroll
      for (int m = 0; m < 4; ++m)
        #pragma unroll
        for (int n = 0; n < 2; ++n)
          acc[m][n] = __builtin_amdgcn_mfma_f32_16x16x32_bf16(aR[m][kf], bR[n][kf], acc[m][n], 0, 0, 0);
    __builtin_amdgcn_s_setprio(0); SCHEDB();
    BAR();

    #pragma unroll
    for (int n = 2; n < 4; ++n) {
      bR[n][0] = *(const bf16x8*)(lds + bbase + (n * 16 + lr) * 128 + sx0);
      bR[n][1] = *(const bf16x8*)(lds + bbase + (n * 16 + lr) * 128 + sx1);
    }
    if (b + 1 < nkt) { STAGE_HALF(Ab, m0 + 128 + srow, b + 1, ASL((b + 1) & 1, 1)); }
    BAR(); WAITLG0; SCHEDB();
    __builtin_amdgcn_s_setprio(1);
    #pragma unroll
    for (int kf = 0; kf < 2; ++kf)
      #pragma unroll
      for (int m = 0; m < 4; ++m)
        #pragma unroll
        for (int n = 2; n < 4; ++n)
          acc[m][n] = __builtin_amdgcn_mfma_f32_16x16x32_bf16(aR[m][kf], bR[n][kf], acc[m][n], 0, 0, 0);
    __builtin_amdgcn_s_setprio(0); SCHEDB();
    BAR();

    #pragma unroll
    for (int m = 0; m < 4; ++m) {
      aR[m][0] = *(const bf16x8*)(lds + abase + ((m + 4) * 16 + lr) * 128 + sx0);
      aR[m][1] = *(const bf16x8*)(lds + abase + ((m + 4) * 16 + lr) * 128 + sx1);
    }
    if (b + 2 < nkt) { STAGE_HALF(Bb, n0 + srow, b + 2, BSL(p, 0)); }
    BAR(); WAITLG0; SCHEDB();
    __builtin_amdgcn_s_setprio(1);
    #pragma unroll
    for (int kf = 0; kf < 2; ++kf)
      #pragma unroll
      for (int m = 0; m < 4; ++m)
        #pragma unroll
        for (int n = 0; n < 2; ++n)
          acc[m + 4][n] = __builtin_amdgcn_mfma_f32_16x16x32_bf16(aR[m][kf], bR[n][kf], acc[m + 4][n], 0, 0, 0);
    __builtin_amdgcn_s_setprio(0); SCHEDB();
    BAR();

    if (b + 2 < nkt) { STAGE_HALF(Bb, n0 + 128 + srow, b + 2, BSL(p, 1)); }
    BAR(); SCHEDB();
    __builtin_amdgcn_s_setprio(1);
    #pragma unroll
    for (int kf = 0; kf < 2; ++kf)
      #pragma unroll
      for (int m = 0; m < 4; ++m)
        #pragma unroll
        for (int n = 2; n < 4; ++n)
          acc[m + 4][n] = __builtin_amdgcn_mfma_f32_16x16x32_bf16(aR[m][kf], bR[n][kf], acc[m + 4][n], 0, 0, 0);
    __builtin_amdgcn_s_setprio(0); SCHEDB();
    if (b + 2 < nkt) { WAITVM4; } else { WAITVM0; }
    BAR();
  }

  // ---- epilogue ----
  if (EPI == 0) {
    #pragma unroll
    for (int m = 0; m < 8; ++m) {
      const int row0 = m0 + wr * 128 + m * 16 + lg * 4;
      #pragma unroll
      for (int n = 0; n < 4; ++n) {
        const int col = n0 + wc * 64 + n * 16 + lr;
        #pragma unroll
        for (int r = 0; r < 4; ++r)
          __builtin_nontemporal_store(acc[m][n][r], &Cf[(size_t)(row0 + r) * N + col]);
      }
    }
  } else if (EPI == 1) {
    int hh[4], dd[4]; float inv[4]; bool rope[4];
    #pragma unroll
    for (int n = 0; n < 4; ++n) {
      int col = n0 + wc * 64 + n * 16 + lr;
      hh[n] = col / 192;
      dd[n] = col - hh[n] * 192;
      rope[n] = (dd[n] >= 128);
      int i = (dd[n] - 128) >> 1;
      inv[n] = rope[n] ? exp2f(-(float)i * 0.41524101186092f) : 0.f;
    }
    const bool odd = (lr & 1);
    #pragma unroll
    for (int m = 0; m < 8; ++m) {
      const int row0 = m0 + wr * 128 + m * 16 + lg * 4;
      #pragma unroll
      for (int r = 0; r < 4; ++r) {
        const int row = row0 + r;
        const float pv = (float)pos[row];
        #pragma unroll
        for (int n = 0; n < 4; ++n) {
          float v = acc[m][n][r];
          float o = __shfl_xor(v, 1, 64);
          if (rope[n]) {
            float s, c;
            __sincosf(pv * inv[n], &s, &c);
            v = odd ? (o * s + v * c) : (v * c - o * s);
          }
          q_all[((size_t)hh[n] * 2048 + row) * 192 + dd[n]] = f2bf(v);
        }
      }
    }
  } else if (EPI == 2) {
    // kv: col -> (h = col>>8, dd). dd<128 -> k_all nope; dd>=128 -> v_t packed u16x4.
    #pragma unroll
    for (int n = 0; n < 4; ++n) {
      const int col = n0 + wc * 64 + n * 16 + lr;
      const int h = col >> 8, dd = col & 255;
      if (dd < 128) {
        #pragma unroll
        for (int m = 0; m < 8; ++m) {
          const int row0 = m0 + wr * 128 + m * 16 + lg * 4;
          #pragma unroll
          for (int r = 0; r < 4; ++r)
            k_all[((size_t)h * 2048 + row0 + r) * 200 + dd] = f2bf(acc[m][n][r]);
        }
      } else {
        u16* vb = v_t + ((size_t)h * 128 + (dd - 128)) * 2048;
        #pragma unroll
        for (int m = 0; m < 8; ++m) {
          const int row0 = m0 + wr * 128 + m * 16 + lg * 4;
          u16x4 o;
          o[0] = f2bf(acc[m][n][0]); o[1] = f2bf(acc[m][n][1]);
          o[2] = f2bf(acc[m][n][2]); o[3] = f2bf(acc[m][n][3]);
          *(u16x4*)(vb + row0) = o;
        }
      }
    }
  } else {
    // bf16 C to q_all pointer (slab buffer), stride N
    #pragma unroll
    for (int m = 0; m < 8; ++m) {
      const int row0 = m0 + wr * 128 + m * 16 + lg * 4;
      #pragma unroll
      for (int n = 0; n < 4; ++n) {
        const int col = n0 + wc * 64 + n * 16 + lr;
        #pragma unroll
        for (int r = 0; r < 4; ++r)
          q_all[(size_t)(row0 + r) * N + col] = f2bf(acc[m][n][r]);
      }
    }
  }
#undef ASL
#undef BSL
#undef STAGE_HALF
}

// ---------- LoRA-A GEMM: 8-phase 256^2, Npad=2304, split-K=3 into bf16 slabs ----------
#define SLAB2 ((size_t)2048 * 2304)
__global__ __launch_bounds__(512, 2) void gemm_a8(const u16* __restrict__ A,
                                                  const u16* __restrict__ Bt,
                                                  u16* __restrict__ C) {
  __shared__ char lds[131072];
  const int z = blockIdx.x / 72;                 // 0..2
  const int wg = blockIdx.x - z * 72;
  const int nkt = (z == 2) ? 26 : 27;            // 27+27+26 = 80 k-tiles (K=5120)
  gemm8_body<3>(lds, A, Bt, 2304, 5120, wg, 72, 9, nkt, z * 27,
                nullptr, C + (size_t)z * SLAB2, nullptr, nullptr, nullptr);
}

// ---------- fused q_b + kv_b launch with fused epilogues (kv writes v_t directly) ----------
__global__ __launch_bounds__(512, 2) void gemm_fused_b(const u16* __restrict__ A1,
                                                       const u16* __restrict__ B1,
                                                       const u16* __restrict__ A2,
                                                       const u16* __restrict__ B2,
                                                       const int* __restrict__ pos,
                                                       u16* __restrict__ q_all,
                                                       u16* __restrict__ k_all,
                                                       u16* __restrict__ v_t) {
  __shared__ char lds[131072];
  if (blockIdx.x < 192)
    gemm8_body<1>(lds, A1, B1, 6144, 1536, blockIdx.x, 192, 24, 24, 0, pos, q_all, nullptr, nullptr, nullptr);
  else
    gemm8_body<2>(lds, A2, B2, 8192, 512, blockIdx.x - 192, 256, 32, 8, 0, pos, nullptr, k_all, v_t, nullptr);
}

// ---------- out-projection (8-phase 256^2, f32 C nontemporal) ----------
__global__ __launch_bounds__(512, 2) void gemm_out_k(const u16* __restrict__ A,
                                                     const u16* __restrict__ Bt,
                                                     float* __restrict__ C) {
  __shared__ char lds[131072];
  gemm8_body<0>(lds, A, Bt, 5120, 4096, blockIdx.x, 160, 20, 64, 0,
                nullptr, nullptr, nullptr, nullptr, C);
}

// ---------- merged norms: RMSNorm(q) + RMSNorm(kv) + RoPE(k) + k_all rope broadcast ----------
__global__ __launch_bounds__(256) void norm_all(const u16* __restrict__ slabs,
                                                const float* __restrict__ wq,
                                                const float* __restrict__ wkv,
                                                const int* __restrict__ pos,
                                                u16* __restrict__ q_c_n,
                                                u16* __restrict__ comp,
                                                u16* __restrict__ k_all) {
  const int row = blockIdx.x, tid = threadIdx.x;
  const u16* xr = slabs + (size_t)row * 2304;
  __shared__ float sm[4];
  __shared__ u16 krv[64];

  // ---- q part (cols 0..1535) ----
  float v[6]; float ss = 0.f;
  #pragma unroll
  for (int i = 0; i < 6; ++i) {
    size_t o = tid + i * 256;
    v[i] = b2f(xr[o]) + b2f(xr[o + SLAB2]) + b2f(xr[o + 2 * SLAB2]);
    ss += v[i] * v[i];
  }
  #pragma unroll
  for (int o = 32; o > 0; o >>= 1) ss += __shfl_down(ss, o, 64);
  if ((tid & 63) == 0) sm[tid >> 6] = ss;
  __syncthreads();
  float rsq = rsqrtf((sm[0] + sm[1] + sm[2] + sm[3]) * (1.f / 1536.f) + 1e-6f);
  #pragma unroll
  for (int i = 0; i < 6; ++i)
    q_c_n[(size_t)row * 1536 + tid + i * 256] = f2bf(v[i] * rsq * wq[tid + i * 256]);

  // ---- kv part (cols 1536..2047 norm; 2048..2111 rope) ----
  const u16* xk = xr + 1536;
  float v0 = b2f(xk[tid]) + b2f(xk[tid + SLAB2]) + b2f(xk[tid + 2 * SLAB2]);
  size_t o1 = tid + 256;
  float v1 = b2f(xk[o1]) + b2f(xk[o1 + SLAB2]) + b2f(xk[o1 + 2 * SLAB2]);
  float ss2 = v0 * v0 + v1 * v1;
  #pragma unroll
  for (int o = 32; o > 0; o >>= 1) ss2 += __shfl_down(ss2, o, 64);
  __syncthreads();                    // all sm reads from q-phase done
  if ((tid & 63) == 0) sm[tid >> 6] = ss2;
  if (tid < 32) {
    float p = (float)pos[row];
    float inv = powf(10000.0f, -(float)(2 * tid) * (1.0f / 64.0f));
    float ang = p * inv;
    float c = cosf(ang), s = sinf(ang);
    size_t e1 = 512 + 2 * tid, e2 = e1 + 1;
    float x1 = b2f(xk[e1]) + b2f(xk[e1 + SLAB2]) + b2f(xk[e1 + 2 * SLAB2]);
    float x2 = b2f(xk[e2]) + b2f(xk[e2 + SLAB2]) + b2f(xk[e2 + 2 * SLAB2]);
    krv[2 * tid]     = f2bf(x1 * c - x2 * s);
    krv[2 * tid + 1] = f2bf(x1 * s + x2 * c);
  }
  __syncthreads();
  float rsk = rsqrtf((sm[0] + sm[1] + sm[2] + sm[3]) * (1.f / 512.f) + 1e-6f);
  comp[(size_t)row * 512 + tid]       = f2bf(v0 * rsk * wkv[tid]);
  comp[(size_t)row * 512 + tid + 256] = f2bf(v1 * rsk * wkv[tid + 256]);

  const int h = tid >> 3, j8 = (tid & 7) << 3;
  *(u16x8*)&k_all[((size_t)h * 2048 + row) * 200 + 128 + j8] = *(const u16x8*)&krv[j8];
}

// ---------- flash attention: 8 waves, 128q x 64s tiles, dbuf, swapped-QK, setprio ----------
#define SCL2 0.10412706f
#define THR2 11.5f
__global__ __launch_bounds__(512, 2) void attn_fwd(const u16* __restrict__ q_all,
                                                   const u16* __restrict__ k_all,
                                                   const u16* __restrict__ v_t,
                                                   u16* __restrict__ attnb) {
  __shared__ __align__(16) char lds[106496];
  const int tid = threadIdx.x;
  const int lane = tid & 63, wid = tid >> 6;
  const int lr = lane & 15, lg = lane >> 4;
  const int h = blockIdx.x & 31, bq = blockIdx.x >> 5;

  const char* kh = (const char*)(k_all + (size_t)h * 2048 * 200);
  const char* vh = (const char*)(v_t + (size_t)h * 128 * 2048);
  char* Pw = lds + 88064 + wid * 2304;

  const int nCalls = (wid < 3) ? 6 : 5;
  const char* gp[6]; int cofs[6]; int isK[6];
  #pragma unroll
  for (int ii = 0; ii < 6; ++ii) {
    int i = wid + (ii << 3);
    if (i < 43) {
      int c = (i << 6) + lane;
      cofs[ii] = c << 4;
      if (c < 1600) { gp[ii] = kh + ((size_t)c << 4); isK[ii] = 1; }
      else {
        int cv = c - 1600;
        int row = cv / 9, sub = cv - row * 9;
        gp[ii] = vh + ((size_t)row << 12) + ((sub < 8) ? (sub << 4) : 0);
        isK[ii] = 0;
      }
    } else { gp[ii] = kh; cofs[ii] = 0; isK[ii] = 1; }
  }

#define STAGE(s0_, bOff_)                                                       \
  { int _sk = (s0_) * 400, _sv = (s0_) * 2;                                     \
    _Pragma("unroll")                                                           \
    for (int ii = 0; ii < 6; ++ii)                                              \
      if (ii < nCalls)                                                          \
        gl16(gp[ii] + (isK[ii] ? _sk : _sv), lds + (bOff_) + cofs[ii]); }

#define WAITSTAGE                                                               \
  { if (wid < 3) { asm volatile("s_waitcnt vmcnt(6)" ::: "memory"); }           \
    else        { asm volatile("s_waitcnt vmcnt(5)" ::: "memory"); } }

  const int kRd = lr * 400 + lg * 16;
  const int vRd = lr * 144 + lg * 16;
  const int pRd = lr * 144 + lg * 16;
  const int pWr = lr * 144 + lg * 8;

  #pragma unroll
  for (int half = 0; half < 2; ++half) {
    const int qt = half ? (15 - bq) : bq;
    const int qb0 = qt << 7;
    const int nt = 2 * qt + 2;
    const int qlane = qb0 + wid * 16 + lr;
    const int qwmin = qb0 + wid * 16;

    bf16x8 qf[6];
    const u16* qptr = q_all + ((size_t)h * 2048 + qlane) * 192 + lg * 8;
    #pragma unroll
    for (int kf = 0; kf < 6; ++kf) qf[kf] = *(const bf16x8*)(qptr + kf * 32);

    f32x4 O[8] = {};
    float m = -1e30f, l = 0.f;

    STAGE(0, 0);
    for (int st = 0; st < nt; ++st) {
      const int s0 = st << 6;
      const int bOff = (st & 1) * 44032;
      if (st + 1 < nt) {
        STAGE((st + 1) << 6, ((st + 1) & 1) * 44032);
        WAITSTAGE;
      } else {
        WAITVM0;
      }
      BAR();

      const bool active = (s0 <= qwmin + 15);
      if (active) {
        const char* Kb = lds + bOff;
        const char* Vb = lds + bOff + 25600;

        f32x4 S[4];
        __builtin_amdgcn_s_setprio(1);
        #pragma unroll
        for (int sb = 0; sb < 4; ++sb) {
          f32x4 a = {};
          #pragma unroll
          for (int kf = 0; kf < 6; ++kf) {
            bf16x8 kfr = *(const bf16x8*)(Kb + kRd + sb * 6400 + kf * 64);
            a = __builtin_amdgcn_mfma_f32_16x16x32_bf16(kfr, qf[kf], a, 0, 0, 0);
          }
          S[sb] = a;
        }
        __builtin_amdgcn_s_setprio(0);

        if (s0 + 63 > qwmin) {
          const int kb0 = s0 + lg * 4;
          #pragma unroll
          for (int sb = 0; sb < 4; ++sb)
            #pragma unroll
            for (int r = 0; r < 4; ++r) {
              int k = kb0 + sb * 16 + r;
              S[sb][r] = (k > qlane) ? -1e30f : S[sb][r] * SCL2;
            }
        } else {
          #pragma unroll
          for (int sb = 0; sb < 4; ++sb)
            #pragma unroll
            for (int r = 0; r < 4; ++r) S[sb][r] *= SCL2;
        }

        float mx = S[0][0];
        #pragma unroll
        for (int sb = 0; sb < 4; ++sb)
          #pragma unroll
          for (int r = 0; r < 4; ++r) mx = fmaxf(mx, S[sb][r]);
        mx = fmaxf(mx, __shfl_xor(mx, 16, 64));
        mx = fmaxf(mx, __shfl_xor(mx, 32, 64));

        const bool skip = __all(mx <= m + THR2);
        float alpha = 1.f;
        if (!skip) { float mn = fmaxf(m, mx); alpha = exp2f(m - mn); m = mn; }

        float ps = 0.f;
        #pragma unroll
        for (int sb = 0; sb < 4; ++sb)
          #pragma unroll
          for (int r = 0; r < 4; ++r) {
            float pv = exp2f(S[sb][r] - m);
            S[sb][r] = pv;
            ps += pv;
          }
        ps += __shfl_xor(ps, 16, 64);
        ps += __shfl_xor(ps, 32, 64);
        l = l * alpha + ps;

        if (!skip) {
          float aO[4];
          #pragma unroll
          for (int r = 0; r < 4; ++r) aO[r] = __shfl(alpha, lg * 4 + r, 64);
          #pragma unroll
          for (int nb = 0; nb < 8; ++nb)
            #pragma unroll
            for (int r = 0; r < 4; ++r) O[nb][r] *= aO[r];
        }

        #pragma unroll
        for (int sb = 0; sb < 4; ++sb) {
          u32 p01, p23;
          asm("v_cvt_pk_bf16_f32 %0, %1, %2" : "=v"(p01) : "v"(S[sb][0]), "v"(S[sb][1]));
          asm("v_cvt_pk_bf16_f32 %0, %1, %2" : "=v"(p23) : "v"(S[sb][2]), "v"(S[sb][3]));
          *(uint2*)(Pw + pWr + sb * 32) = make_uint2(p01, p23);
        }

        __builtin_amdgcn_s_setprio(1);
        #pragma unroll
        for (int k2 = 0; k2 < 2; ++k2) {
          bf16x8 pa = *(const bf16x8*)(Pw + pRd + k2 * 64);
          #pragma unroll
          for (int nb = 0; nb < 8; ++nb) {
            bf16x8 vf = *(const bf16x8*)(Vb + vRd + nb * 2304 + k2 * 64);
            O[nb] = __builtin_amdgcn_mfma_f32_16x16x32_bf16(pa, vf, O[nb], 0, 0, 0);
          }
        }
        __builtin_amdgcn_s_setprio(0);
      }
      BAR();
    }

    float rv[4];
    #pragma unroll
    for (int r = 0; r < 4; ++r) rv[r] = 1.f / __shfl(l, lg * 4 + r, 64);
    #pragma unroll
    for (int nb = 0; nb < 8; ++nb) {
      const int col = h * 128 + nb * 16 + lr;
      #pragma unroll
      for (int r = 0; r < 4; ++r)
        attnb[(size_t)(qb0 + wid * 16 + lg * 4 + r) * 4096 + col] = f2bf(O[nb][r] * rv[r]);
    }
  }
#undef STAGE
#undef WAITSTAGE
}

// ---------- host ----------
extern "C" void kernel_launch(void* const* d_in, const int* in_sizes, int n_in,
                              void* d_out, int out_size, void* d_ws, size_t ws_size,
                              hipStream_t stream) {
  const int*   positions = (const int*)d_in[0];
  const float* hidden    = (const float*)d_in[1];
  const float* w_q_a     = (const float*)d_in[2];
  const float* q_a_norm  = (const float*)d_in[3];
  const float* w_q_b     = (const float*)d_in[4];
  const float* w_kv_a    = (const float*)d_in[5];
  const float* kv_a_norm = (const float*)d_in[6];
  const float* w_kv_b    = (const float*)d_in[7];
  const float* w_o       = (const float*)d_in[8];
  float* out = (float*)d_out;
  char*  ws  = (char*)d_ws;

  // layout (bytes), total 203,948,032 (slabs now bf16, fits in old region)
  u16* hs_bf  = (u16*)(ws + 0);
  u16* attnb  = (u16*)(ws + 0);
  u16* wab_t  = (u16*)(ws + 20971520);
  u16* q_c_n  = (u16*)(ws + 20971520);
  u16* comp   = (u16*)(ws + 27262976);
  u16* wqb_t  = (u16*)(ws + 44564480);
  u16* wkvb_t = (u16*)(ws + 63438848);
  u16* wo_t   = (u16*)(ws + 71827456);
  u16* slabs  = (u16*)(ws + 113770496);          // 3 x [2048][2304] bf16 = 28.3M
  u16* q_all  = (u16*)(ws + 113770496);          // aliases slabs (dead after norm_all)
  u16* k_all  = (u16*)(ws + 138936320);
  u16* v_t    = (u16*)(ws + 187170816);

  // 1) all conversions/transposes (separate, high-occupancy)
  prep_w<<<23296, 256, 0, stream>>>(hidden, hs_bf, w_q_a, w_kv_a, wab_t,
                                    w_q_b, wqb_t, w_kv_b, wkvb_t, w_o, wo_t);

  // 2) merged LoRA-A GEMM: 8-phase 256^2, Npad=2304, split-K=3, bf16 slabs
  gemm_a8<<<216, 512, 0, stream>>>(hs_bf, wab_t, slabs);

  // 3) merged norms (+rope broadcast into k_all)
  norm_all<<<2048, 256, 0, stream>>>(slabs, q_a_norm, kv_a_norm, positions,
                                     q_c_n, comp, k_all);

  // 4) fused q_b + kv_b with layout/rope epilogues (kv writes k_all + v_t directly)
  gemm_fused_b<<<448, 512, 0, stream>>>(q_c_n, wqb_t, comp, wkvb_t, positions,
                                        q_all, k_all, v_t);

  // 5) attention
  attn_fwd<<<256, 512, 0, stream>>>(q_all, k_all, v_t, attnb);

  // 6) output projection (8-phase 256^2, 160 blocks, nontemporal C)
  gemm_out_k<<<160, 512, 0, stream>>>(attnb, wo_t, out);
}